// Round 11
// baseline (865.773 us; speedup 1.0000x reference)
//
#include <hip/hip_runtime.h>

#define Bn 64
#define Sn 512
#define EB 768
#define Hn 64
#define G3 192
#define Tn 16
#define Pn 32

__device__ __forceinline__ float sigmoidf_(float x) { return 1.f / (1.f + __expf(-x)); }
__device__ __forceinline__ float tanhf_(float x) { return 1.f - 2.f / (__expf(2.f * x) + 1.f); }

// pack hi16(a) | hi16(b)<<16 in ONE v_perm_b32 (bf16 truncate; threshold 28.96
// makes the <=1ulp rounding difference irrelevant)
__device__ __forceinline__ unsigned pkbf(float a, float b) {
  return __builtin_amdgcn_perm(__float_as_uint(b), __float_as_uint(a), 0x07060302u);
}

typedef __attribute__((ext_vector_type(8))) short short8;
typedef __attribute__((ext_vector_type(4))) float f32x4;

// ================= K_A: gemm (0..767) + qkv (768..895) + wcomb (896..903) ====
__global__ __launch_bounds__(256) void mega_a(const float* __restrict__ A,
                                              const float* __restrict__ Wf,
                                              const float* __restrict__ Wb,
                                              const float* __restrict__ bf,
                                              const float* __restrict__ bb,
                                              float* __restrict__ C,
                                              const float* __restrict__ in2,
                                              const float* __restrict__ Wqkv,
                                              const float* __restrict__ bqkv,
                                              float* __restrict__ qb,
                                              float* __restrict__ kb,
                                              float* __restrict__ vb,
                                              const float* __restrict__ Wdense,
                                              const float* __restrict__ Wfuse,
                                              float* __restrict__ wcomb) {
  __shared__ __align__(16) char smem[20864];
  const int gblk = blockIdx.x;
  const int tid = threadIdx.x;
  if (gblk < 768) {
    // ---- gemm_mfma: XCD-sibling swizzle; +40-pad LDS; perm-packed bf16 staging
    unsigned short* As = (unsigned short*)smem;          // 128*40
    unsigned short* Bs = As + 128 * 40;                  // 128*40
    const int xcd = gblk & 7;
    const int slot = gblk >> 3;
    const int lin = xcd * 96 + slot;
    const int m_tile = lin / 3;
    const int n_tile = lin % 3;
    const int n0 = n_tile * 128;
    const int m0 = m_tile * 128;
    const int wv = tid >> 6;
    const int lane = tid & 63;
    const int wm = (wv >> 1) * 64, wn = (wv & 1) * 64;
    const int fr = lane & 15, fq = lane >> 4;
    const int srow = tid >> 1;
    const int shalf = (tid & 1) * 16;
    const int bcol = n0 + srow;
    const float* Wrow = (bcol < G3) ? (Wf + (size_t)bcol * EB) : (Wb + (size_t)(bcol - G3) * EB);
    const float* Arow = A + (size_t)(m0 + srow) * EB;
    f32x4 acc[4][4];
#pragma unroll
    for (int i = 0; i < 4; ++i)
#pragma unroll
      for (int j = 0; j < 4; ++j) acc[i][j] = (f32x4){0.f, 0.f, 0.f, 0.f};
    for (int k0 = 0; k0 < EB; k0 += 32) {
      float4 a0 = *(const float4*)&Arow[k0 + shalf + 0];
      float4 a1 = *(const float4*)&Arow[k0 + shalf + 4];
      float4 a2 = *(const float4*)&Arow[k0 + shalf + 8];
      float4 a3 = *(const float4*)&Arow[k0 + shalf + 12];
      float4 b0 = *(const float4*)&Wrow[k0 + shalf + 0];
      float4 b1 = *(const float4*)&Wrow[k0 + shalf + 4];
      float4 b2 = *(const float4*)&Wrow[k0 + shalf + 8];
      float4 b3 = *(const float4*)&Wrow[k0 + shalf + 12];
      __syncthreads();
      uint4 w;
      w.x = pkbf(a0.x, a0.y); w.y = pkbf(a0.z, a0.w);
      w.z = pkbf(a1.x, a1.y); w.w = pkbf(a1.z, a1.w);
      *(uint4*)&As[srow * 40 + shalf] = w;
      w.x = pkbf(a2.x, a2.y); w.y = pkbf(a2.z, a2.w);
      w.z = pkbf(a3.x, a3.y); w.w = pkbf(a3.z, a3.w);
      *(uint4*)&As[srow * 40 + shalf + 8] = w;
      w.x = pkbf(b0.x, b0.y); w.y = pkbf(b0.z, b0.w);
      w.z = pkbf(b1.x, b1.y); w.w = pkbf(b1.z, b1.w);
      *(uint4*)&Bs[srow * 40 + shalf] = w;
      w.x = pkbf(b2.x, b2.y); w.y = pkbf(b2.z, b2.w);
      w.z = pkbf(b3.x, b3.y); w.w = pkbf(b3.z, b3.w);
      *(uint4*)&Bs[srow * 40 + shalf + 8] = w;
      __syncthreads();
      short8 af[4], bfv[4];
#pragma unroll
      for (int i = 0; i < 4; ++i) af[i] = *(short8*)&As[(wm + i * 16 + fr) * 40 + fq * 8];
#pragma unroll
      for (int j = 0; j < 4; ++j) bfv[j] = *(short8*)&Bs[(wn + j * 16 + fr) * 40 + fq * 8];
#pragma unroll
      for (int i = 0; i < 4; ++i)
#pragma unroll
        for (int j = 0; j < 4; ++j)
          acc[i][j] = __builtin_amdgcn_mfma_f32_16x16x32_bf16(af[i], bfv[j], acc[i][j], 0, 0, 0);
    }
#pragma unroll
    for (int j = 0; j < 4; ++j) {
      int col = n0 + wn + j * 16 + fr;
      float bias = (col < G3) ? bf[col] : bb[col - G3];
#pragma unroll
      for (int i = 0; i < 4; ++i) {
        int rowb = m0 + wm + i * 16 + fq * 4;
#pragma unroll
        for (int rg = 0; rg < 4; ++rg)
          C[(size_t)(rowb + rg) * 384 + col] = acc[i][j][rg] + bias;
      }
    }
  } else if (gblk < 896) {
    // ---- qkv projection
    float* Ws = (float*)smem;          // 96*32
    float* bs = Ws + 96 * 32;          // 96
    for (int i = tid; i < 96 * 32; i += 256) Ws[i] = Wqkv[i];
    if (tid < 96) bs[tid] = bqkv[tid];
    __syncthreads();
    const int idx = (gblk - 768) * 256 + tid;
    float x[32];
#pragma unroll
    for (int d4 = 0; d4 < 8; ++d4) {
      float4 v = *(const float4*)&in2[(size_t)idx * 32 + d4 * 4];
      x[d4 * 4 + 0] = v.x; x[d4 * 4 + 1] = v.y; x[d4 * 4 + 2] = v.z; x[d4 * 4 + 3] = v.w;
    }
    float* const dsts[3] = {qb, kb, vb};
#pragma unroll
    for (int p = 0; p < 3; ++p) {
      float a[32];
#pragma unroll
      for (int j = 0; j < 32; ++j) {
        float s = bs[p * 32 + j];
#pragma unroll
        for (int d = 0; d < 32; ++d) s += x[d] * Ws[(p * 32 + j) * 32 + d];
        a[j] = s;
      }
      float* dst = dsts[p];
#pragma unroll
      for (int j4 = 0; j4 < 8; ++j4) {
        float4 o = {a[j4 * 4 + 0], a[j4 * 4 + 1], a[j4 * 4 + 2], a[j4 * 4 + 3]};
        *(float4*)&dst[(size_t)idx * 32 + j4 * 4] = o;
      }
    }
  } else {
    // ---- wcomb
    int e = (gblk - 896) * 256 + tid;
    int i = e >> 4, j = e & 15;
    float a = 0.f;
#pragma unroll
    for (int c = 0; c < 16; ++c) a += Wdense[i * 16 + c] * Wfuse[c * 16 + j];
    wcomb[e] = a;
  }
}

// ================= K_B: gru (0..127) + attn_split (128..639) =================
__global__ __launch_bounds__(256, 1) void mega_b(const float* __restrict__ C,
                                                 const float* __restrict__ Whh_f,
                                                 const float* __restrict__ bhh_f,
                                                 const float* __restrict__ Whh_b,
                                                 const float* __restrict__ bhh_b,
                                                 float* __restrict__ out,
                                                 const float* __restrict__ qb,
                                                 const float* __restrict__ kb,
                                                 const float* __restrict__ vb,
                                                 float* __restrict__ part) {
  __shared__ __align__(16) char smem[33280];
  const int tid = threadIdx.x;
  if (blockIdx.x < 128) {
    // ---- gru (R5 structure, 230 µs; 48 wt floats/lane = VGPR-safe)
    float* xs = (float*)smem;            // 32*192
    float* hbuf = xs + 32 * 192;         // 2*64
    float* obuf = hbuf + 128;            // 32*64
    const int wg = blockIdx.x;
    const int rev = (wg >= Bn) ? 1 : 0;
    const int b = wg & (Bn - 1);
    const int w = tid >> 6;
    const int lane = tid & 63;
    const int r = lane >> 2;
    const int kc = lane & 3;
    const int row = 16 * w + r;
    const int k0 = 16 * kc;
    const float* Whh = rev ? Whh_b : Whh_f;
    const float* bhh = rev ? bhh_b : bhh_f;
    const int colBase = rev ? G3 : 0;
    const int dirOff = rev ? Hn : 0;
    float4 wv[3][4];
#pragma unroll
    for (int g = 0; g < 3; ++g)
#pragma unroll
      for (int q = 0; q < 4; ++q) {
        wv[g][q] = *(const float4*)&Whh[(size_t)(g * 64 + row) * 64 + k0 + 4 * q];
        asm volatile("" : "+v"(wv[g][q].x), "+v"(wv[g][q].y), "+v"(wv[g][q].z), "+v"(wv[g][q].w));
      }
    const float brr = bhh[row], bzz = bhh[64 + row], bnn = bhh[128 + row];
    if (tid < 64) { hbuf[tid] = 0.f; hbuf[64 + tid] = 0.f; }
    float h = 0.f;
    for (int c = 0; c < 16; ++c) {
      const int cstart = c * 32;
      if (c > 0) {
#pragma unroll
        for (int i = 0; i < 2; ++i) {
          int f = tid + 256 * i;
          int s = f >> 4;
          int c4 = (f & 15) << 2;
          int tp = cstart - 32 + s;
          int orow = rev ? (Sn - 1 - tp) : tp;
          *(float4*)&out[(size_t)(b * Sn + orow) * 128 + dirOff + c4] = *(const float4*)&obuf[s * 64 + c4];
        }
      }
      float4 st[6];
#pragma unroll
      for (int i = 0; i < 6; ++i) {
        int f = tid + 256 * i;
        int s = f / 48;
        int c4 = (f % 48) << 2;
        int t = cstart + s;
        int grow = rev ? (Sn - 1 - t) : t;
        st[i] = *(const float4*)&C[(size_t)(b * Sn + grow) * 384 + colBase + c4];
      }
#pragma unroll
      for (int i = 0; i < 6; ++i) {
        int f = tid + 256 * i;
        int s = f / 48;
        int c4 = (f % 48) << 2;
        *(float4*)&xs[s * 192 + c4] = st[i];
      }
      __syncthreads();
      float xr = xs[row], xz = xs[64 + row], xn = xs[128 + row];
      for (int s = 0; s < 32; ++s) {
        const int t = cstart + s;
        const int p = t & 1;
        float4 ha = *(const float4*)&hbuf[p * 64 + k0 + 0];
        float4 hb = *(const float4*)&hbuf[p * 64 + k0 + 4];
        float4 hc = *(const float4*)&hbuf[p * 64 + k0 + 8];
        float4 hd = *(const float4*)&hbuf[p * 64 + k0 + 12];
        float nxr = 0.f, nxz = 0.f, nxn = 0.f;
        if (s + 1 < 32) {
          const float* xq = &xs[(s + 1) * 192];
          nxr = xq[row]; nxz = xq[64 + row]; nxn = xq[128 + row];
        }
        float dr, dz, dn;
        {
          float4 wa, wbv, wc, wd;
          wa = wv[0][0]; wbv = wv[0][1]; wc = wv[0][2]; wd = wv[0][3];
          dr = (wa.x * ha.x + wa.y * ha.y + wa.z * ha.z + wa.w * ha.w)
             + (wbv.x * hb.x + wbv.y * hb.y + wbv.z * hb.z + wbv.w * hb.w)
             + (wc.x * hc.x + wc.y * hc.y + wc.z * hc.z + wc.w * hc.w)
             + (wd.x * hd.x + wd.y * hd.y + wd.z * hd.z + wd.w * hd.w);
          wa = wv[1][0]; wbv = wv[1][1]; wc = wv[1][2]; wd = wv[1][3];
          dz = (wa.x * ha.x + wa.y * ha.y + wa.z * ha.z + wa.w * ha.w)
             + (wbv.x * hb.x + wbv.y * hb.y + wbv.z * hb.z + wbv.w * hb.w)
             + (wc.x * hc.x + wc.y * hc.y + wc.z * hc.z + wc.w * hc.w)
             + (wd.x * hd.x + wd.y * hd.y + wd.z * hd.z + wd.w * hd.w);
          wa = wv[2][0]; wbv = wv[2][1]; wc = wv[2][2]; wd = wv[2][3];
          dn = (wa.x * ha.x + wa.y * ha.y + wa.z * ha.z + wa.w * ha.w)
             + (wbv.x * hb.x + wbv.y * hb.y + wbv.z * hb.z + wbv.w * hb.w)
             + (wc.x * hc.x + wc.y * hc.y + wc.z * hc.z + wc.w * hc.w)
             + (wd.x * hd.x + wd.y * hd.y + wd.z * hd.z + wd.w * hd.w);
        }
        dr += __shfl_xor(dr, 1); dr += __shfl_xor(dr, 2);
        dz += __shfl_xor(dz, 1); dz += __shfl_xor(dz, 2);
        dn += __shfl_xor(dn, 1); dn += __shfl_xor(dn, 2);
        float rg = sigmoidf_(xr + brr + dr);
        float zg = sigmoidf_(xz + bzz + dz);
        float ng = tanhf_(xn + rg * (bnn + dn));
        h = (1.f - zg) * ng + zg * h;
        if (kc == 0) {
          hbuf[(p ^ 1) * 64 + row] = h;
          obuf[s * 64 + row] = h;
        }
        __syncthreads();
        xr = nxr; xz = nxz; xn = nxn;
      }
    }
#pragma unroll
    for (int i = 0; i < 2; ++i) {
      int f = tid + 256 * i;
      int s = f >> 4;
      int c4 = (f & 15) << 2;
      int tp = Sn - 32 + s;
      int orow = rev ? (Sn - 1 - tp) : tp;
      *(float4*)&out[(size_t)(b * Sn + orow) * 128 + dirOff + c4] = *(const float4*)&obuf[s * 64 + c4];
    }
  } else {
    // ---- attn_split (flash-style split-K partials)
    float* Ks = (float*)smem;           // 128*32
    float* Vs = Ks + 128 * 32;          // 128*32
    const int blk = blockIdx.x - 128;
    const int b = blk >> 3;
    const int qhalf = (blk >> 2) & 1;
    const int split = blk & 3;
    const int k0 = split * 128;
#pragma unroll
    for (int i = 0; i < 4; ++i) {
      int f = tid + 256 * i;
      int row = f >> 3, col = (f & 7) * 4;
      *(float4*)&Ks[row * 32 + col] = *(const float4*)&kb[(size_t)(b * Sn + k0 + row) * 32 + col];
      *(float4*)&Vs[row * 32 + col] = *(const float4*)&vb[(size_t)(b * Sn + k0 + row) * 32 + col];
    }
    const int q = b * Sn + qhalf * 256 + tid;
    float qv[32];
#pragma unroll
    for (int d4 = 0; d4 < 8; ++d4) {
      float4 v = *(const float4*)&qb[(size_t)q * 32 + d4 * 4];
      qv[d4 * 4 + 0] = v.x; qv[d4 * 4 + 1] = v.y; qv[d4 * 4 + 2] = v.z; qv[d4 * 4 + 3] = v.w;
    }
    __syncthreads();
    const float scale = 0.17677669529663687f;
    float m = -1e30f, lsum = 0.f;
    float acc[32] = {};
    for (int kk = 0; kk < 128; ++kk) {
      const float4* kr = (const float4*)&Ks[kk * 32];
      float s = 0.f;
#pragma unroll
      for (int d4 = 0; d4 < 8; ++d4) {
        float4 kv = kr[d4];
        s += qv[d4 * 4 + 0] * kv.x + qv[d4 * 4 + 1] * kv.y + qv[d4 * 4 + 2] * kv.z + qv[d4 * 4 + 3] * kv.w;
      }
      s *= scale;
      float mn = fmaxf(m, s);
      float e1 = __expf(m - mn);
      float p = __expf(s - mn);
      lsum = lsum * e1 + p;
      const float4* vr = (const float4*)&Vs[kk * 32];
#pragma unroll
      for (int d4 = 0; d4 < 8; ++d4) {
        float4 vv = vr[d4];
        acc[d4 * 4 + 0] = acc[d4 * 4 + 0] * e1 + p * vv.x;
        acc[d4 * 4 + 1] = acc[d4 * 4 + 1] * e1 + p * vv.y;
        acc[d4 * 4 + 2] = acc[d4 * 4 + 2] * e1 + p * vv.z;
        acc[d4 * 4 + 3] = acc[d4 * 4 + 3] * e1 + p * vv.w;
      }
      m = mn;
    }
    float* rec = part + ((size_t)q * 4 + split) * 36;
#pragma unroll
    for (int d4 = 0; d4 < 8; ++d4) {
      float4 o = {acc[d4 * 4 + 0], acc[d4 * 4 + 1], acc[d4 * 4 + 2], acc[d4 * 4 + 3]};
      *(float4*)&rec[d4 * 4] = o;
    }
    rec[32] = m;
    rec[33] = lsum;
  }
}

// ========== K_C: combine partials + out_proj + emissions (fused) =============
__global__ __launch_bounds__(256) void comb_emis(const float* __restrict__ part,
                                                 const float* __restrict__ Wout,
                                                 const float* __restrict__ bout,
                                                 const float* __restrict__ lstm,
                                                 const float* __restrict__ wcomb,
                                                 const float* __restrict__ Wfuse,
                                                 float* __restrict__ emis) {
  __shared__ float Ws[32 * 32];
  __shared__ float bs[32];
  __shared__ float Wc[128 * 16];
  __shared__ float Wf2[32 * 16];
  const int tid = threadIdx.x;
  for (int i = tid; i < 1024; i += 256) Ws[i] = Wout[i];
  if (tid < 32) bs[tid] = bout[tid];
  for (int i = tid; i < 2048; i += 256) Wc[i] = wcomb[i];
  for (int i = tid; i < 512; i += 256) Wf2[i] = Wfuse[16 * 16 + i];
  __syncthreads();
  const int q = blockIdx.x * 256 + tid;
  const float* rec = part + (size_t)q * 4 * 36;
  float m0 = rec[32], m1 = rec[36 + 32], m2 = rec[72 + 32], m3 = rec[108 + 32];
  float M = fmaxf(fmaxf(m0, m1), fmaxf(m2, m3));
  float w0 = __expf(m0 - M), w1 = __expf(m1 - M), w2 = __expf(m2 - M), w3 = __expf(m3 - M);
  float L = rec[33] * w0 + rec[36 + 33] * w1 + rec[72 + 33] * w2 + rec[108 + 33] * w3;
  float inv = 1.f / L;
  float a[32];
#pragma unroll
  for (int d4 = 0; d4 < 8; ++d4) {
    float4 p0 = *(const float4*)&rec[d4 * 4];
    float4 p1 = *(const float4*)&rec[36 + d4 * 4];
    float4 p2 = *(const float4*)&rec[72 + d4 * 4];
    float4 p3 = *(const float4*)&rec[108 + d4 * 4];
    a[d4 * 4 + 0] = (p0.x * w0 + p1.x * w1 + p2.x * w2 + p3.x * w3) * inv;
    a[d4 * 4 + 1] = (p0.y * w0 + p1.y * w1 + p2.y * w2 + p3.y * w3) * inv;
    a[d4 * 4 + 2] = (p0.z * w0 + p1.z * w1 + p2.z * w2 + p3.z * w3) * inv;
    a[d4 * 4 + 3] = (p0.w * w0 + p1.w * w1 + p2.w * w2 + p3.w * w3) * inv;
  }
  float o[32];
#pragma unroll
  for (int j = 0; j < 32; ++j) {
    float s = bs[j];
#pragma unroll
    for (int d = 0; d < 32; ++d) s += a[d] * Ws[j * 32 + d];
    o[j] = s;
  }
  float acc[16] = {};
  for (int i = 0; i < 128; i += 4) {
    float4 lv = *(const float4*)&lstm[(size_t)q * 128 + i];
    float ll[4] = {lv.x, lv.y, lv.z, lv.w};
#pragma unroll
    for (int u = 0; u < 4; ++u)
#pragma unroll
      for (int j = 0; j < 16; ++j) acc[j] += ll[u] * Wc[(i + u) * 16 + j];
  }
#pragma unroll
  for (int d = 0; d < 32; ++d)
#pragma unroll
    for (int j = 0; j < 16; ++j) acc[j] += o[d] * Wf2[d * 16 + j];
#pragma unroll
  for (int j = 0; j < 16; j += 4) {
    float4 ov = {acc[j], acc[j + 1], acc[j + 2], acc[j + 3]};
    *(float4*)&emis[(size_t)q * 16 + j] = ov;
  }
}

// ======= K_E: numer (blocks 0..63) + denom x4-interleaved (64..79) ===========
__global__ __launch_bounds__(64) void mega_e(const float* __restrict__ emis,
                                             const int* __restrict__ tgt,
                                             const float* __restrict__ cstart,
                                             const float* __restrict__ cend,
                                             const float* __restrict__ ctrans,
                                             float* __restrict__ numer,
                                             float* __restrict__ denom) {
  if (blockIdx.x < 64) {
    const int b = blockIdx.x, l = threadIdx.x;
    float ssum = 0.f;
    for (int t = l; t < Sn; t += 64) {
      int tg = tgt[b * Sn + t];
      ssum += emis[(size_t)(b * Sn + t) * Tn + tg];
      if (t + 1 < Sn) {
        int tg2 = tgt[b * Sn + t + 1];
        ssum += ctrans[tg * Tn + tg2];
      }
    }
    if (l == 0) ssum += cstart[tgt[b * Sn]] + cend[tgt[b * Sn + Sn - 1]];
    for (int off = 32; off > 0; off >>= 1) ssum += __shfl_down(ssum, off);
    if (l == 0) numer[b] = ssum;
  } else {
    // 4 independent batch-scans interleaved per block: latency of shfl/exp
    // chains overlaps (chain was the bound, not issue width)
    const int b0 = (blockIdx.x - 64) * 4;
    const int lane = threadIdx.x;
    const int g = lane >> 4;
    const int j = lane & 15;
    const int i0 = 4 * g;
    float tr0 = ctrans[(i0 + 0) * Tn + j];
    float tr1 = ctrans[(i0 + 1) * Tn + j];
    float tr2 = ctrans[(i0 + 2) * Tn + j];
    float tr3 = ctrans[(i0 + 3) * Tn + j];
    const float cs = cstart[j];
    float sB[4], emB[4];
#pragma unroll
    for (int u = 0; u < 4; ++u) {
      sB[u] = cs + emis[(size_t)((b0 + u) * Sn) * Tn + j];
      emB[u] = emis[(size_t)((b0 + u) * Sn + 1) * Tn + j];
    }
    for (int t = 1; t < Sn; ++t) {
#pragma unroll
      for (int u = 0; u < 4; ++u) {
        float s0 = __shfl(sB[u], i0 + 0);
        float s1 = __shfl(sB[u], i0 + 1);
        float s2 = __shfl(sB[u], i0 + 2);
        float s3 = __shfl(sB[u], i0 + 3);
        float v0 = s0 + tr0, v1 = s1 + tr1, v2 = s2 + tr2, v3 = s3 + tr3;
        float m = fmaxf(fmaxf(v0, v1), fmaxf(v2, v3));
        m = fmaxf(m, __shfl_xor(m, 16));
        m = fmaxf(m, __shfl_xor(m, 32));
        float e = __expf(v0 - m) + __expf(v1 - m) + __expf(v2 - m) + __expf(v3 - m);
        e += __shfl_xor(e, 16);
        e += __shfl_xor(e, 32);
        float em_cur = emB[u];
        if (t + 1 < Sn) emB[u] = emis[(size_t)((b0 + u) * Sn + t + 1) * Tn + j];
        sB[u] = em_cur + m + __logf(e);
      }
    }
    const float ce = cend[j];
#pragma unroll
    for (int u = 0; u < 4; ++u) {
      float f = sB[u] + ce;
      float m = f;
      m = fmaxf(m, __shfl_xor(m, 1));
      m = fmaxf(m, __shfl_xor(m, 2));
      m = fmaxf(m, __shfl_xor(m, 4));
      m = fmaxf(m, __shfl_xor(m, 8));
      float e = __expf(f - m);
      e += __shfl_xor(e, 1);
      e += __shfl_xor(e, 2);
      e += __shfl_xor(e, 4);
      e += __shfl_xor(e, 8);
      if (lane == 0) denom[b0 + u] = m + __logf(e);
    }
  }
}

// ---------------- K_F: final scalar ------------------------------------------
__global__ __launch_bounds__(64) void final_kernel(const float* __restrict__ numer,
                                                   const float* __restrict__ denom,
                                                   float* __restrict__ out) {
  const int l = threadIdx.x;
  float d = denom[l] - numer[l];
  for (int off = 32; off > 0; off >>= 1) d += __shfl_down(d, off);
  if (l == 0) out[0] = d * (1.f / 64.f);
}

extern "C" void kernel_launch(void* const* d_in, const int* in_sizes, int n_in,
                              void* d_out, int out_size, void* d_ws, size_t ws_size,
                              hipStream_t stream) {
  (void)in_sizes; (void)n_in; (void)out_size; (void)ws_size;
  const float* bert = (const float*)d_in[0];
  const float* in2 = (const float*)d_in[1];
  const int* tgt = (const int*)d_in[2];
  const float* Wih_f = (const float*)d_in[3];
  const float* Whh_f = (const float*)d_in[4];
  const float* bih_f = (const float*)d_in[5];
  const float* bhh_f = (const float*)d_in[6];
  const float* Wih_b = (const float*)d_in[7];
  const float* Whh_b = (const float*)d_in[8];
  const float* bih_b = (const float*)d_in[9];
  const float* bhh_b = (const float*)d_in[10];
  const float* Wdense = (const float*)d_in[11];
  const float* in_proj_w = (const float*)d_in[12];
  const float* in_proj_b = (const float*)d_in[13];
  const float* out_proj_w = (const float*)d_in[14];
  const float* out_proj_b = (const float*)d_in[15];
  const float* Wfuse = (const float*)d_in[16];
  const float* cstart = (const float*)d_in[17];
  const float* cend = (const float*)d_in[18];
  const float* ctrans = (const float*)d_in[19];

  float* ws = (float*)d_ws;
  float* C = ws;                                    // B*S*384
  float* lstm = C + (size_t)Bn * Sn * 384;          // B*S*128
  float* qb = lstm + (size_t)Bn * Sn * 2 * Hn;      // B*S*32
  float* kb = qb + (size_t)Bn * Sn * Pn;
  float* vb = kb + (size_t)Bn * Sn * Pn;
  float* emis = vb + (size_t)Bn * Sn * Pn;          // B*S*16
  float* wcomb = emis + (size_t)Bn * Sn * Tn;       // 2048
  float* numer = wcomb + 2048;                      // 64
  float* denom = numer + Bn;                        // 64
  float* part = denom + Bn;                         // 32768*4*36 floats (18.9 MB)

  mega_a<<<904, 256, 0, stream>>>(bert, Wih_f, Wih_b, bih_f, bih_b, C,
                                  in2, in_proj_w, in_proj_b, qb, kb, vb,
                                  Wdense, Wfuse, wcomb);
  mega_b<<<640, 256, 0, stream>>>(C, Whh_f, bhh_f, Whh_b, bhh_b, lstm,
                                  qb, kb, vb, part);
  comb_emis<<<Bn * Sn / 256, 256, 0, stream>>>(part, out_proj_w, out_proj_b,
                                               lstm, wcomb, Wfuse, emis);
  mega_e<<<80, 64, 0, stream>>>(emis, tgt, cstart, cend, ctrans, numer, denom);
  final_kernel<<<1, 64, 0, stream>>>(numer, denom, (float*)d_out);
}

// Round 12
// 693.086 us; speedup vs baseline: 1.2492x; 1.2492x over previous
//
#include <hip/hip_runtime.h>

#define Bn 64
#define Sn 512
#define EB 768
#define Hn 64
#define G3 192
#define Tn 16
#define Pn 32

__device__ __forceinline__ float sigmoidf_(float x) { return 1.f / (1.f + __expf(-x)); }
__device__ __forceinline__ float tanhf_(float x) { return 1.f - 2.f / (__expf(2.f * x) + 1.f); }

// pack hi16(a) | hi16(b)<<16 in ONE v_perm_b32 (bf16 truncate)
__device__ __forceinline__ unsigned pkbf(float a, float b) {
  return __builtin_amdgcn_perm(__float_as_uint(b), __float_as_uint(a), 0x07060302u);
}

typedef __attribute__((ext_vector_type(8))) short short8;
typedef __attribute__((ext_vector_type(4))) float f32x4;

// ================= K_A: gemm (0..767) + qkv (768..895) + wcomb (896..903) ====
__global__ __launch_bounds__(256) void mega_a(const float* __restrict__ A,
                                              const float* __restrict__ Wf,
                                              const float* __restrict__ Wb,
                                              const float* __restrict__ bf,
                                              const float* __restrict__ bb,
                                              float* __restrict__ C,
                                              const float* __restrict__ in2,
                                              const float* __restrict__ Wqkv,
                                              const float* __restrict__ bqkv,
                                              float* __restrict__ qb,
                                              float* __restrict__ kb,
                                              float* __restrict__ vb,
                                              const float* __restrict__ Wdense,
                                              const float* __restrict__ Wfuse,
                                              float* __restrict__ wcomb) {
  __shared__ __align__(16) char smem[20864];
  const int gblk = blockIdx.x;
  const int tid = threadIdx.x;
  if (gblk < 768) {
    // ---- gemm_mfma: XCD-sibling swizzle; +40-pad LDS; perm-packed bf16 staging
    unsigned short* As = (unsigned short*)smem;          // 128*40
    unsigned short* Bs = As + 128 * 40;                  // 128*40
    const int xcd = gblk & 7;
    const int slot = gblk >> 3;
    const int lin = xcd * 96 + slot;
    const int m_tile = lin / 3;
    const int n_tile = lin % 3;
    const int n0 = n_tile * 128;
    const int m0 = m_tile * 128;
    const int wv = tid >> 6;
    const int lane = tid & 63;
    const int wm = (wv >> 1) * 64, wn = (wv & 1) * 64;
    const int fr = lane & 15, fq = lane >> 4;
    const int srow = tid >> 1;
    const int shalf = (tid & 1) * 16;
    const int bcol = n0 + srow;
    const float* Wrow = (bcol < G3) ? (Wf + (size_t)bcol * EB) : (Wb + (size_t)(bcol - G3) * EB);
    const float* Arow = A + (size_t)(m0 + srow) * EB;
    f32x4 acc[4][4];
#pragma unroll
    for (int i = 0; i < 4; ++i)
#pragma unroll
      for (int j = 0; j < 4; ++j) acc[i][j] = (f32x4){0.f, 0.f, 0.f, 0.f};
    for (int k0 = 0; k0 < EB; k0 += 32) {
      float4 a0 = *(const float4*)&Arow[k0 + shalf + 0];
      float4 a1 = *(const float4*)&Arow[k0 + shalf + 4];
      float4 a2 = *(const float4*)&Arow[k0 + shalf + 8];
      float4 a3 = *(const float4*)&Arow[k0 + shalf + 12];
      float4 b0 = *(const float4*)&Wrow[k0 + shalf + 0];
      float4 b1 = *(const float4*)&Wrow[k0 + shalf + 4];
      float4 b2 = *(const float4*)&Wrow[k0 + shalf + 8];
      float4 b3 = *(const float4*)&Wrow[k0 + shalf + 12];
      __syncthreads();
      uint4 w;
      w.x = pkbf(a0.x, a0.y); w.y = pkbf(a0.z, a0.w);
      w.z = pkbf(a1.x, a1.y); w.w = pkbf(a1.z, a1.w);
      *(uint4*)&As[srow * 40 + shalf] = w;
      w.x = pkbf(a2.x, a2.y); w.y = pkbf(a2.z, a2.w);
      w.z = pkbf(a3.x, a3.y); w.w = pkbf(a3.z, a3.w);
      *(uint4*)&As[srow * 40 + shalf + 8] = w;
      w.x = pkbf(b0.x, b0.y); w.y = pkbf(b0.z, b0.w);
      w.z = pkbf(b1.x, b1.y); w.w = pkbf(b1.z, b1.w);
      *(uint4*)&Bs[srow * 40 + shalf] = w;
      w.x = pkbf(b2.x, b2.y); w.y = pkbf(b2.z, b2.w);
      w.z = pkbf(b3.x, b3.y); w.w = pkbf(b3.z, b3.w);
      *(uint4*)&Bs[srow * 40 + shalf + 8] = w;
      __syncthreads();
      short8 af[4], bfv[4];
#pragma unroll
      for (int i = 0; i < 4; ++i) af[i] = *(short8*)&As[(wm + i * 16 + fr) * 40 + fq * 8];
#pragma unroll
      for (int j = 0; j < 4; ++j) bfv[j] = *(short8*)&Bs[(wn + j * 16 + fr) * 40 + fq * 8];
#pragma unroll
      for (int i = 0; i < 4; ++i)
#pragma unroll
        for (int j = 0; j < 4; ++j)
          acc[i][j] = __builtin_amdgcn_mfma_f32_16x16x32_bf16(af[i], bfv[j], acc[i][j], 0, 0, 0);
    }
#pragma unroll
    for (int j = 0; j < 4; ++j) {
      int col = n0 + wn + j * 16 + fr;
      float bias = (col < G3) ? bf[col] : bb[col - G3];
#pragma unroll
      for (int i = 0; i < 4; ++i) {
        int rowb = m0 + wm + i * 16 + fq * 4;
#pragma unroll
        for (int rg = 0; rg < 4; ++rg)
          C[(size_t)(rowb + rg) * 384 + col] = acc[i][j][rg] + bias;
      }
    }
  } else if (gblk < 896) {
    // ---- qkv projection
    float* Ws = (float*)smem;          // 96*32
    float* bs = Ws + 96 * 32;          // 96
    for (int i = tid; i < 96 * 32; i += 256) Ws[i] = Wqkv[i];
    if (tid < 96) bs[tid] = bqkv[tid];
    __syncthreads();
    const int idx = (gblk - 768) * 256 + tid;
    float x[32];
#pragma unroll
    for (int d4 = 0; d4 < 8; ++d4) {
      float4 v = *(const float4*)&in2[(size_t)idx * 32 + d4 * 4];
      x[d4 * 4 + 0] = v.x; x[d4 * 4 + 1] = v.y; x[d4 * 4 + 2] = v.z; x[d4 * 4 + 3] = v.w;
    }
    float* const dsts[3] = {qb, kb, vb};
#pragma unroll
    for (int p = 0; p < 3; ++p) {
      float a[32];
#pragma unroll
      for (int j = 0; j < 32; ++j) {
        float s = bs[p * 32 + j];
#pragma unroll
        for (int d = 0; d < 32; ++d) s += x[d] * Ws[(p * 32 + j) * 32 + d];
        a[j] = s;
      }
      float* dst = dsts[p];
#pragma unroll
      for (int j4 = 0; j4 < 8; ++j4) {
        float4 o = {a[j4 * 4 + 0], a[j4 * 4 + 1], a[j4 * 4 + 2], a[j4 * 4 + 3]};
        *(float4*)&dst[(size_t)idx * 32 + j4 * 4] = o;
      }
    }
  } else {
    // ---- wcomb
    int e = (gblk - 896) * 256 + tid;
    int i = e >> 4, j = e & 15;
    float a = 0.f;
#pragma unroll
    for (int c = 0; c < 16; ++c) a += Wdense[i * 16 + c] * Wfuse[c * 16 + j];
    wcomb[e] = a;
  }
}

// ================= K_B: gru (0..127) + attn_split (128..639) =================
__global__ __launch_bounds__(256, 1) void mega_b(const float* __restrict__ C,
                                                 const float* __restrict__ Whh_f,
                                                 const float* __restrict__ bhh_f,
                                                 const float* __restrict__ Whh_b,
                                                 const float* __restrict__ bhh_b,
                                                 float* __restrict__ out,
                                                 const float* __restrict__ qb,
                                                 const float* __restrict__ kb,
                                                 const float* __restrict__ vb,
                                                 float* __restrict__ part) {
  __shared__ __align__(16) char smem[33280];
  const int tid = threadIdx.x;
  if (blockIdx.x < 128) {
    // ---- gru (R5 structure, 230 µs; 48 wt floats/lane = VGPR-safe)
    float* xs = (float*)smem;            // 32*192
    float* hbuf = xs + 32 * 192;         // 2*64
    float* obuf = hbuf + 128;            // 32*64
    const int wg = blockIdx.x;
    const int rev = (wg >= Bn) ? 1 : 0;
    const int b = wg & (Bn - 1);
    const int w = tid >> 6;
    const int lane = tid & 63;
    const int r = lane >> 2;
    const int kc = lane & 3;
    const int row = 16 * w + r;
    const int k0 = 16 * kc;
    const float* Whh = rev ? Whh_b : Whh_f;
    const float* bhh = rev ? bhh_b : bhh_f;
    const int colBase = rev ? G3 : 0;
    const int dirOff = rev ? Hn : 0;
    float4 wv[3][4];
#pragma unroll
    for (int g = 0; g < 3; ++g)
#pragma unroll
      for (int q = 0; q < 4; ++q) {
        wv[g][q] = *(const float4*)&Whh[(size_t)(g * 64 + row) * 64 + k0 + 4 * q];
        asm volatile("" : "+v"(wv[g][q].x), "+v"(wv[g][q].y), "+v"(wv[g][q].z), "+v"(wv[g][q].w));
      }
    const float brr = bhh[row], bzz = bhh[64 + row], bnn = bhh[128 + row];
    if (tid < 64) { hbuf[tid] = 0.f; hbuf[64 + tid] = 0.f; }
    float h = 0.f;
    for (int c = 0; c < 16; ++c) {
      const int cstart = c * 32;
      if (c > 0) {
#pragma unroll
        for (int i = 0; i < 2; ++i) {
          int f = tid + 256 * i;
          int s = f >> 4;
          int c4 = (f & 15) << 2;
          int tp = cstart - 32 + s;
          int orow = rev ? (Sn - 1 - tp) : tp;
          *(float4*)&out[(size_t)(b * Sn + orow) * 128 + dirOff + c4] = *(const float4*)&obuf[s * 64 + c4];
        }
      }
      float4 st[6];
#pragma unroll
      for (int i = 0; i < 6; ++i) {
        int f = tid + 256 * i;
        int s = f / 48;
        int c4 = (f % 48) << 2;
        int t = cstart + s;
        int grow = rev ? (Sn - 1 - t) : t;
        st[i] = *(const float4*)&C[(size_t)(b * Sn + grow) * 384 + colBase + c4];
      }
#pragma unroll
      for (int i = 0; i < 6; ++i) {
        int f = tid + 256 * i;
        int s = f / 48;
        int c4 = (f % 48) << 2;
        *(float4*)&xs[s * 192 + c4] = st[i];
      }
      __syncthreads();
      float xr = xs[row], xz = xs[64 + row], xn = xs[128 + row];
      for (int s = 0; s < 32; ++s) {
        const int t = cstart + s;
        const int p = t & 1;
        float4 ha = *(const float4*)&hbuf[p * 64 + k0 + 0];
        float4 hb = *(const float4*)&hbuf[p * 64 + k0 + 4];
        float4 hc = *(const float4*)&hbuf[p * 64 + k0 + 8];
        float4 hd = *(const float4*)&hbuf[p * 64 + k0 + 12];
        float nxr = 0.f, nxz = 0.f, nxn = 0.f;
        if (s + 1 < 32) {
          const float* xq = &xs[(s + 1) * 192];
          nxr = xq[row]; nxz = xq[64 + row]; nxn = xq[128 + row];
        }
        float dr, dz, dn;
        {
          float4 wa, wbv, wc, wd;
          wa = wv[0][0]; wbv = wv[0][1]; wc = wv[0][2]; wd = wv[0][3];
          dr = (wa.x * ha.x + wa.y * ha.y + wa.z * ha.z + wa.w * ha.w)
             + (wbv.x * hb.x + wbv.y * hb.y + wbv.z * hb.z + wbv.w * hb.w)
             + (wc.x * hc.x + wc.y * hc.y + wc.z * hc.z + wc.w * hc.w)
             + (wd.x * hd.x + wd.y * hd.y + wd.z * hd.z + wd.w * hd.w);
          wa = wv[1][0]; wbv = wv[1][1]; wc = wv[1][2]; wd = wv[1][3];
          dz = (wa.x * ha.x + wa.y * ha.y + wa.z * ha.z + wa.w * ha.w)
             + (wbv.x * hb.x + wbv.y * hb.y + wbv.z * hb.z + wbv.w * hb.w)
             + (wc.x * hc.x + wc.y * hc.y + wc.z * hc.z + wc.w * hc.w)
             + (wd.x * hd.x + wd.y * hd.y + wd.z * hd.z + wd.w * hd.w);
          wa = wv[2][0]; wbv = wv[2][1]; wc = wv[2][2]; wd = wv[2][3];
          dn = (wa.x * ha.x + wa.y * ha.y + wa.z * ha.z + wa.w * ha.w)
             + (wbv.x * hb.x + wbv.y * hb.y + wbv.z * hb.z + wbv.w * hb.w)
             + (wc.x * hc.x + wc.y * hc.y + wc.z * hc.z + wc.w * hc.w)
             + (wd.x * hd.x + wd.y * hd.y + wd.z * hd.z + wd.w * hd.w);
        }
        dr += __shfl_xor(dr, 1); dr += __shfl_xor(dr, 2);
        dz += __shfl_xor(dz, 1); dz += __shfl_xor(dz, 2);
        dn += __shfl_xor(dn, 1); dn += __shfl_xor(dn, 2);
        float rg = sigmoidf_(xr + brr + dr);
        float zg = sigmoidf_(xz + bzz + dz);
        float ng = tanhf_(xn + rg * (bnn + dn));
        h = (1.f - zg) * ng + zg * h;
        if (kc == 0) {
          hbuf[(p ^ 1) * 64 + row] = h;
          obuf[s * 64 + row] = h;
        }
        __syncthreads();
        xr = nxr; xz = nxz; xn = nxn;
      }
    }
#pragma unroll
    for (int i = 0; i < 2; ++i) {
      int f = tid + 256 * i;
      int s = f >> 4;
      int c4 = (f & 15) << 2;
      int tp = Sn - 32 + s;
      int orow = rev ? (Sn - 1 - tp) : tp;
      *(float4*)&out[(size_t)(b * Sn + orow) * 128 + dirOff + c4] = *(const float4*)&obuf[s * 64 + c4];
    }
  } else {
    // ---- attn_split (flash-style split-K partials)
    float* Ks = (float*)smem;           // 128*32
    float* Vs = Ks + 128 * 32;          // 128*32
    const int blk = blockIdx.x - 128;
    const int b = blk >> 3;
    const int qhalf = (blk >> 2) & 1;
    const int split = blk & 3;
    const int k0 = split * 128;
#pragma unroll
    for (int i = 0; i < 4; ++i) {
      int f = tid + 256 * i;
      int row = f >> 3, col = (f & 7) * 4;
      *(float4*)&Ks[row * 32 + col] = *(const float4*)&kb[(size_t)(b * Sn + k0 + row) * 32 + col];
      *(float4*)&Vs[row * 32 + col] = *(const float4*)&vb[(size_t)(b * Sn + k0 + row) * 32 + col];
    }
    const int q = b * Sn + qhalf * 256 + tid;
    float qv[32];
#pragma unroll
    for (int d4 = 0; d4 < 8; ++d4) {
      float4 v = *(const float4*)&qb[(size_t)q * 32 + d4 * 4];
      qv[d4 * 4 + 0] = v.x; qv[d4 * 4 + 1] = v.y; qv[d4 * 4 + 2] = v.z; qv[d4 * 4 + 3] = v.w;
    }
    __syncthreads();
    const float scale = 0.17677669529663687f;
    float m = -1e30f, lsum = 0.f;
    float acc[32] = {};
    for (int kk = 0; kk < 128; ++kk) {
      const float4* kr = (const float4*)&Ks[kk * 32];
      float s = 0.f;
#pragma unroll
      for (int d4 = 0; d4 < 8; ++d4) {
        float4 kv = kr[d4];
        s += qv[d4 * 4 + 0] * kv.x + qv[d4 * 4 + 1] * kv.y + qv[d4 * 4 + 2] * kv.z + qv[d4 * 4 + 3] * kv.w;
      }
      s *= scale;
      float mn = fmaxf(m, s);
      float e1 = __expf(m - mn);
      float p = __expf(s - mn);
      lsum = lsum * e1 + p;
      const float4* vr = (const float4*)&Vs[kk * 32];
#pragma unroll
      for (int d4 = 0; d4 < 8; ++d4) {
        float4 vv = vr[d4];
        acc[d4 * 4 + 0] = acc[d4 * 4 + 0] * e1 + p * vv.x;
        acc[d4 * 4 + 1] = acc[d4 * 4 + 1] * e1 + p * vv.y;
        acc[d4 * 4 + 2] = acc[d4 * 4 + 2] * e1 + p * vv.z;
        acc[d4 * 4 + 3] = acc[d4 * 4 + 3] * e1 + p * vv.w;
      }
      m = mn;
    }
    float* rec = part + ((size_t)q * 4 + split) * 36;
#pragma unroll
    for (int d4 = 0; d4 < 8; ++d4) {
      float4 o = {acc[d4 * 4 + 0], acc[d4 * 4 + 1], acc[d4 * 4 + 2], acc[d4 * 4 + 3]};
      *(float4*)&rec[d4 * 4] = o;
    }
    rec[32] = m;
    rec[33] = lsum;
  }
}

// ========== K_C: combine partials + out_proj + emissions (fused) =============
__global__ __launch_bounds__(256) void comb_emis(const float* __restrict__ part,
                                                 const float* __restrict__ Wout,
                                                 const float* __restrict__ bout,
                                                 const float* __restrict__ lstm,
                                                 const float* __restrict__ wcomb,
                                                 const float* __restrict__ Wfuse,
                                                 float* __restrict__ emis) {
  __shared__ float Ws[32 * 32];
  __shared__ float bs[32];
  __shared__ float Wc[128 * 16];
  __shared__ float Wf2[32 * 16];
  const int tid = threadIdx.x;
  for (int i = tid; i < 1024; i += 256) Ws[i] = Wout[i];
  if (tid < 32) bs[tid] = bout[tid];
  for (int i = tid; i < 2048; i += 256) Wc[i] = wcomb[i];
  for (int i = tid; i < 512; i += 256) Wf2[i] = Wfuse[16 * 16 + i];
  __syncthreads();
  const int q = blockIdx.x * 256 + tid;
  const float* rec = part + (size_t)q * 4 * 36;
  float m0 = rec[32], m1 = rec[36 + 32], m2 = rec[72 + 32], m3 = rec[108 + 32];
  float M = fmaxf(fmaxf(m0, m1), fmaxf(m2, m3));
  float w0 = __expf(m0 - M), w1 = __expf(m1 - M), w2 = __expf(m2 - M), w3 = __expf(m3 - M);
  float L = rec[33] * w0 + rec[36 + 33] * w1 + rec[72 + 33] * w2 + rec[108 + 33] * w3;
  float inv = 1.f / L;
  float a[32];
#pragma unroll
  for (int d4 = 0; d4 < 8; ++d4) {
    float4 p0 = *(const float4*)&rec[d4 * 4];
    float4 p1 = *(const float4*)&rec[36 + d4 * 4];
    float4 p2 = *(const float4*)&rec[72 + d4 * 4];
    float4 p3 = *(const float4*)&rec[108 + d4 * 4];
    a[d4 * 4 + 0] = (p0.x * w0 + p1.x * w1 + p2.x * w2 + p3.x * w3) * inv;
    a[d4 * 4 + 1] = (p0.y * w0 + p1.y * w1 + p2.y * w2 + p3.y * w3) * inv;
    a[d4 * 4 + 2] = (p0.z * w0 + p1.z * w1 + p2.z * w2 + p3.z * w3) * inv;
    a[d4 * 4 + 3] = (p0.w * w0 + p1.w * w1 + p2.w * w2 + p3.w * w3) * inv;
  }
  float o[32];
#pragma unroll
  for (int j = 0; j < 32; ++j) {
    float s = bs[j];
#pragma unroll
    for (int d = 0; d < 32; ++d) s += a[d] * Ws[j * 32 + d];
    o[j] = s;
  }
  float acc[16] = {};
  for (int i = 0; i < 128; i += 4) {
    float4 lv = *(const float4*)&lstm[(size_t)q * 128 + i];
    float ll[4] = {lv.x, lv.y, lv.z, lv.w};
#pragma unroll
    for (int u = 0; u < 4; ++u)
#pragma unroll
      for (int j = 0; j < 16; ++j) acc[j] += ll[u] * Wc[(i + u) * 16 + j];
  }
#pragma unroll
  for (int d = 0; d < 32; ++d)
#pragma unroll
    for (int j = 0; j < 16; ++j) acc[j] += o[d] * Wf2[d * 16 + j];
#pragma unroll
  for (int j = 0; j < 16; j += 4) {
    float4 ov = {acc[j], acc[j + 1], acc[j + 2], acc[j + 3]};
    *(float4*)&emis[(size_t)q * 16 + j] = ov;
  }
}

// ================= K_E: numer (0..63) + denom (64..127), single-chain ========
__global__ __launch_bounds__(64) void mega_e(const float* __restrict__ emis,
                                             const int* __restrict__ tgt,
                                             const float* __restrict__ cstart,
                                             const float* __restrict__ cend,
                                             const float* __restrict__ ctrans,
                                             float* __restrict__ numer,
                                             float* __restrict__ denom) {
  if (blockIdx.x < 64) {
    const int b = blockIdx.x, l = threadIdx.x;
    float ssum = 0.f;
    for (int t = l; t < Sn; t += 64) {
      int tg = tgt[b * Sn + t];
      ssum += emis[(size_t)(b * Sn + t) * Tn + tg];
      if (t + 1 < Sn) {
        int tg2 = tgt[b * Sn + t + 1];
        ssum += ctrans[tg * Tn + tg2];
      }
    }
    if (l == 0) ssum += cstart[tgt[b * Sn]] + cend[tgt[b * Sn + Sn - 1]];
    for (int off = 32; off > 0; off >>= 1) ssum += __shfl_down(ssum, off);
    if (l == 0) numer[b] = ssum;
  } else {
    const int b = blockIdx.x - 64;
    const int lane = threadIdx.x;
    const int g = lane >> 4;
    const int j = lane & 15;
    const int i0 = 4 * g;
    float tr0 = ctrans[(i0 + 0) * Tn + j];
    float tr1 = ctrans[(i0 + 1) * Tn + j];
    float tr2 = ctrans[(i0 + 2) * Tn + j];
    float tr3 = ctrans[(i0 + 3) * Tn + j];
    float s = cstart[j] + emis[(size_t)(b * Sn) * Tn + j];
    float em = emis[(size_t)(b * Sn + 1) * Tn + j];
    for (int t = 1; t < Sn; ++t) {
      float s0 = __shfl(s, i0 + 0);
      float s1 = __shfl(s, i0 + 1);
      float s2 = __shfl(s, i0 + 2);
      float s3 = __shfl(s, i0 + 3);
      float v0 = s0 + tr0, v1 = s1 + tr1, v2 = s2 + tr2, v3 = s3 + tr3;
      float m = fmaxf(fmaxf(v0, v1), fmaxf(v2, v3));
      m = fmaxf(m, __shfl_xor(m, 16));
      m = fmaxf(m, __shfl_xor(m, 32));
      float e = __expf(v0 - m) + __expf(v1 - m) + __expf(v2 - m) + __expf(v3 - m);
      e += __shfl_xor(e, 16);
      e += __shfl_xor(e, 32);
      float em_cur = em;
      if (t + 1 < Sn) em = emis[(size_t)(b * Sn + t + 1) * Tn + j];
      s = em_cur + m + __logf(e);
    }
    float f = s + cend[j];
    float m = f;
    m = fmaxf(m, __shfl_xor(m, 1));
    m = fmaxf(m, __shfl_xor(m, 2));
    m = fmaxf(m, __shfl_xor(m, 4));
    m = fmaxf(m, __shfl_xor(m, 8));
    float e = __expf(f - m);
    e += __shfl_xor(e, 1);
    e += __shfl_xor(e, 2);
    e += __shfl_xor(e, 4);
    e += __shfl_xor(e, 8);
    if (lane == 0) denom[b] = m + __logf(e);
  }
}

// ---------------- K_F: final scalar ------------------------------------------
__global__ __launch_bounds__(64) void final_kernel(const float* __restrict__ numer,
                                                   const float* __restrict__ denom,
                                                   float* __restrict__ out) {
  const int l = threadIdx.x;
  float d = denom[l] - numer[l];
  for (int off = 32; off > 0; off >>= 1) d += __shfl_down(d, off);
  if (l == 0) out[0] = d * (1.f / 64.f);
}

extern "C" void kernel_launch(void* const* d_in, const int* in_sizes, int n_in,
                              void* d_out, int out_size, void* d_ws, size_t ws_size,
                              hipStream_t stream) {
  (void)in_sizes; (void)n_in; (void)out_size; (void)ws_size;
  const float* bert = (const float*)d_in[0];
  const float* in2 = (const float*)d_in[1];
  const int* tgt = (const int*)d_in[2];
  const float* Wih_f = (const float*)d_in[3];
  const float* Whh_f = (const float*)d_in[4];
  const float* bih_f = (const float*)d_in[5];
  const float* bhh_f = (const float*)d_in[6];
  const float* Wih_b = (const float*)d_in[7];
  const float* Whh_b = (const float*)d_in[8];
  const float* bih_b = (const float*)d_in[9];
  const float* bhh_b = (const float*)d_in[10];
  const float* Wdense = (const float*)d_in[11];
  const float* in_proj_w = (const float*)d_in[12];
  const float* in_proj_b = (const float*)d_in[13];
  const float* out_proj_w = (const float*)d_in[14];
  const float* out_proj_b = (const float*)d_in[15];
  const float* Wfuse = (const float*)d_in[16];
  const float* cstart = (const float*)d_in[17];
  const float* cend = (const float*)d_in[18];
  const float* ctrans = (const float*)d_in[19];

  float* ws = (float*)d_ws;
  float* C = ws;                                    // B*S*384
  float* lstm = C + (size_t)Bn * Sn * 384;          // B*S*128
  float* qb = lstm + (size_t)Bn * Sn * 2 * Hn;      // B*S*32
  float* kb = qb + (size_t)Bn * Sn * Pn;
  float* vb = kb + (size_t)Bn * Sn * Pn;
  float* emis = vb + (size_t)Bn * Sn * Pn;          // B*S*16
  float* wcomb = emis + (size_t)Bn * Sn * Tn;       // 2048
  float* numer = wcomb + 2048;                      // 64
  float* denom = numer + Bn;                        // 64
  float* part = denom + Bn;                         // 32768*4*36 floats (18.9 MB)

  mega_a<<<904, 256, 0, stream>>>(bert, Wih_f, Wih_b, bih_f, bih_b, C,
                                  in2, in_proj_w, in_proj_b, qb, kb, vb,
                                  Wdense, Wfuse, wcomb);
  mega_b<<<640, 256, 0, stream>>>(C, Whh_f, bhh_f, Whh_b, bhh_b, lstm,
                                  qb, kb, vb, part);
  comb_emis<<<Bn * Sn / 256, 256, 0, stream>>>(part, out_proj_w, out_proj_b,
                                               lstm, wcomb, Wfuse, emis);
  mega_e<<<128, 64, 0, stream>>>(emis, tgt, cstart, cend, ctrans, numer, denom);
  final_kernel<<<1, 64, 0, stream>>>(numer, denom, (float*)d_out);
}

// Round 13
// 545.322 us; speedup vs baseline: 1.5876x; 1.2710x over previous
//
#include <hip/hip_runtime.h>

#define Bn 64
#define Sn 512
#define EB 768
#define Hn 64
#define G3 192
#define Tn 16
#define Pn 32

__device__ __forceinline__ float sigmoidf_(float x) { return 1.f / (1.f + __expf(-x)); }
__device__ __forceinline__ float tanhf_(float x) { return 1.f - 2.f / (__expf(2.f * x) + 1.f); }

__device__ __forceinline__ unsigned short f2bf(float x) {
  union { float f; unsigned u; } v; v.f = x;
  unsigned r = v.u + 0x7fff + ((v.u >> 16) & 1);  // RNE
  return (unsigned short)(r >> 16);
}

typedef __attribute__((ext_vector_type(8))) short short8;
typedef __attribute__((ext_vector_type(4))) float f32x4;

// ================= K_A: gemm (0..767) + qkv (768..895) + wcomb (896..903) ====
// (R8-measured-good staging: f2bf RNE, +40-pad LDS)
__global__ __launch_bounds__(256) void mega_a(const float* __restrict__ A,
                                              const float* __restrict__ Wf,
                                              const float* __restrict__ Wb,
                                              const float* __restrict__ bf,
                                              const float* __restrict__ bb,
                                              float* __restrict__ C,
                                              const float* __restrict__ in2,
                                              const float* __restrict__ Wqkv,
                                              const float* __restrict__ bqkv,
                                              float* __restrict__ qb,
                                              float* __restrict__ kb,
                                              float* __restrict__ vb,
                                              const float* __restrict__ Wdense,
                                              const float* __restrict__ Wfuse,
                                              float* __restrict__ wcomb) {
  __shared__ __align__(16) char smem[20864];
  const int gblk = blockIdx.x;
  const int tid = threadIdx.x;
  if (gblk < 768) {
    unsigned short* As = (unsigned short*)smem;          // 128*40
    unsigned short* Bs = As + 128 * 40;                  // 128*40
    const int xcd = gblk & 7;
    const int slot = gblk >> 3;
    const int lin = xcd * 96 + slot;
    const int m_tile = lin / 3;
    const int n_tile = lin % 3;
    const int n0 = n_tile * 128;
    const int m0 = m_tile * 128;
    const int wv = tid >> 6;
    const int lane = tid & 63;
    const int wm = (wv >> 1) * 64, wn = (wv & 1) * 64;
    const int fr = lane & 15, fq = lane >> 4;
    const int srow = tid >> 1;
    const int shalf = (tid & 1) * 16;
    const int bcol = n0 + srow;
    const float* Wrow = (bcol < G3) ? (Wf + (size_t)bcol * EB) : (Wb + (size_t)(bcol - G3) * EB);
    const float* Arow = A + (size_t)(m0 + srow) * EB;
    f32x4 acc[4][4];
#pragma unroll
    for (int i = 0; i < 4; ++i)
#pragma unroll
      for (int j = 0; j < 4; ++j) acc[i][j] = (f32x4){0.f, 0.f, 0.f, 0.f};
    for (int k0 = 0; k0 < EB; k0 += 32) {
      float4 a0 = *(const float4*)&Arow[k0 + shalf + 0];
      float4 a1 = *(const float4*)&Arow[k0 + shalf + 4];
      float4 a2 = *(const float4*)&Arow[k0 + shalf + 8];
      float4 a3 = *(const float4*)&Arow[k0 + shalf + 12];
      float4 b0 = *(const float4*)&Wrow[k0 + shalf + 0];
      float4 b1 = *(const float4*)&Wrow[k0 + shalf + 4];
      float4 b2 = *(const float4*)&Wrow[k0 + shalf + 8];
      float4 b3 = *(const float4*)&Wrow[k0 + shalf + 12];
      __syncthreads();
      short8 pa, pb;
      pa[0] = f2bf(a0.x); pa[1] = f2bf(a0.y); pa[2] = f2bf(a0.z); pa[3] = f2bf(a0.w);
      pa[4] = f2bf(a1.x); pa[5] = f2bf(a1.y); pa[6] = f2bf(a1.z); pa[7] = f2bf(a1.w);
      *(short8*)&As[srow * 40 + shalf] = pa;
      pa[0] = f2bf(a2.x); pa[1] = f2bf(a2.y); pa[2] = f2bf(a2.z); pa[3] = f2bf(a2.w);
      pa[4] = f2bf(a3.x); pa[5] = f2bf(a3.y); pa[6] = f2bf(a3.z); pa[7] = f2bf(a3.w);
      *(short8*)&As[srow * 40 + shalf + 8] = pa;
      pb[0] = f2bf(b0.x); pb[1] = f2bf(b0.y); pb[2] = f2bf(b0.z); pb[3] = f2bf(b0.w);
      pb[4] = f2bf(b1.x); pb[5] = f2bf(b1.y); pb[6] = f2bf(b1.z); pb[7] = f2bf(b1.w);
      *(short8*)&Bs[srow * 40 + shalf] = pb;
      pb[0] = f2bf(b2.x); pb[1] = f2bf(b2.y); pb[2] = f2bf(b2.z); pb[3] = f2bf(b2.w);
      pb[4] = f2bf(b3.x); pb[5] = f2bf(b3.y); pb[6] = f2bf(b3.z); pb[7] = f2bf(b3.w);
      *(short8*)&Bs[srow * 40 + shalf + 8] = pb;
      __syncthreads();
      short8 af[4], bfv[4];
#pragma unroll
      for (int i = 0; i < 4; ++i) af[i] = *(short8*)&As[(wm + i * 16 + fr) * 40 + fq * 8];
#pragma unroll
      for (int j = 0; j < 4; ++j) bfv[j] = *(short8*)&Bs[(wn + j * 16 + fr) * 40 + fq * 8];
#pragma unroll
      for (int i = 0; i < 4; ++i)
#pragma unroll
        for (int j = 0; j < 4; ++j)
          acc[i][j] = __builtin_amdgcn_mfma_f32_16x16x32_bf16(af[i], bfv[j], acc[i][j], 0, 0, 0);
    }
#pragma unroll
    for (int j = 0; j < 4; ++j) {
      int col = n0 + wn + j * 16 + fr;
      float bias = (col < G3) ? bf[col] : bb[col - G3];
#pragma unroll
      for (int i = 0; i < 4; ++i) {
        int rowb = m0 + wm + i * 16 + fq * 4;
#pragma unroll
        for (int rg = 0; rg < 4; ++rg)
          C[(size_t)(rowb + rg) * 384 + col] = acc[i][j][rg] + bias;
      }
    }
  } else if (gblk < 896) {
    float* Ws = (float*)smem;          // 96*32
    float* bs = Ws + 96 * 32;          // 96
    for (int i = tid; i < 96 * 32; i += 256) Ws[i] = Wqkv[i];
    if (tid < 96) bs[tid] = bqkv[tid];
    __syncthreads();
    const int idx = (gblk - 768) * 256 + tid;
    float x[32];
#pragma unroll
    for (int d4 = 0; d4 < 8; ++d4) {
      float4 v = *(const float4*)&in2[(size_t)idx * 32 + d4 * 4];
      x[d4 * 4 + 0] = v.x; x[d4 * 4 + 1] = v.y; x[d4 * 4 + 2] = v.z; x[d4 * 4 + 3] = v.w;
    }
    float* const dsts[3] = {qb, kb, vb};
#pragma unroll
    for (int p = 0; p < 3; ++p) {
      float a[32];
#pragma unroll
      for (int j = 0; j < 32; ++j) {
        float s = bs[p * 32 + j];
#pragma unroll
        for (int d = 0; d < 32; ++d) s += x[d] * Ws[(p * 32 + j) * 32 + d];
        a[j] = s;
      }
      float* dst = dsts[p];
#pragma unroll
      for (int j4 = 0; j4 < 8; ++j4) {
        float4 o = {a[j4 * 4 + 0], a[j4 * 4 + 1], a[j4 * 4 + 2], a[j4 * 4 + 3]};
        *(float4*)&dst[(size_t)idx * 32 + j4 * 4] = o;
      }
    }
  } else {
    int e = (gblk - 896) * 256 + tid;
    int i = e >> 4, j = e & 15;
    float a = 0.f;
#pragma unroll
    for (int c = 0; c < 16; ++c) a += Wdense[i * 16 + c] * Wfuse[c * 16 + j];
    wcomb[e] = a;
  }
}

// ================= K_B: gru (0..127) + attn_split (128..639) =================
__global__ __launch_bounds__(256, 1) void mega_b(const float* __restrict__ C,
                                                 const float* __restrict__ Whh_f,
                                                 const float* __restrict__ bhh_f,
                                                 const float* __restrict__ Whh_b,
                                                 const float* __restrict__ bhh_b,
                                                 float* __restrict__ out,
                                                 const float* __restrict__ qb,
                                                 const float* __restrict__ kb,
                                                 const float* __restrict__ vb,
                                                 float* __restrict__ part) {
  __shared__ __align__(16) char smem[33280];
  const int tid = threadIdx.x;
  if (blockIdx.x < 128) {
    float* xs = (float*)smem;            // 32*192
    float* hbuf = xs + 32 * 192;         // 2*64
    float* obuf = hbuf + 128;            // 32*64
    const int wg = blockIdx.x;
    const int rev = (wg >= Bn) ? 1 : 0;
    const int b = wg & (Bn - 1);
    const int w = tid >> 6;
    const int lane = tid & 63;
    const int r = lane >> 2;
    const int kc = lane & 3;
    const int row = 16 * w + r;
    const int k0 = 16 * kc;
    const float* Whh = rev ? Whh_b : Whh_f;
    const float* bhh = rev ? bhh_b : bhh_f;
    const int colBase = rev ? G3 : 0;
    const int dirOff = rev ? Hn : 0;
    float4 wv[3][4];
#pragma unroll
    for (int g = 0; g < 3; ++g)
#pragma unroll
      for (int q = 0; q < 4; ++q) {
        wv[g][q] = *(const float4*)&Whh[(size_t)(g * 64 + row) * 64 + k0 + 4 * q];
        asm volatile("" : "+v"(wv[g][q].x), "+v"(wv[g][q].y), "+v"(wv[g][q].z), "+v"(wv[g][q].w));
      }
    const float brr = bhh[row], bzz = bhh[64 + row], bnn = bhh[128 + row];
    if (tid < 64) { hbuf[tid] = 0.f; hbuf[64 + tid] = 0.f; }
    float h = 0.f;
    for (int c = 0; c < 16; ++c) {
      const int cstart = c * 32;
      if (c > 0) {
#pragma unroll
        for (int i = 0; i < 2; ++i) {
          int f = tid + 256 * i;
          int s = f >> 4;
          int c4 = (f & 15) << 2;
          int tp = cstart - 32 + s;
          int orow = rev ? (Sn - 1 - tp) : tp;
          *(float4*)&out[(size_t)(b * Sn + orow) * 128 + dirOff + c4] = *(const float4*)&obuf[s * 64 + c4];
        }
      }
      float4 st[6];
#pragma unroll
      for (int i = 0; i < 6; ++i) {
        int f = tid + 256 * i;
        int s = f / 48;
        int c4 = (f % 48) << 2;
        int t = cstart + s;
        int grow = rev ? (Sn - 1 - t) : t;
        st[i] = *(const float4*)&C[(size_t)(b * Sn + grow) * 384 + colBase + c4];
      }
#pragma unroll
      for (int i = 0; i < 6; ++i) {
        int f = tid + 256 * i;
        int s = f / 48;
        int c4 = (f % 48) << 2;
        *(float4*)&xs[s * 192 + c4] = st[i];
      }
      __syncthreads();
      float xr = xs[row], xz = xs[64 + row], xn = xs[128 + row];
      for (int s = 0; s < 32; ++s) {
        const int t = cstart + s;
        const int p = t & 1;
        float4 ha = *(const float4*)&hbuf[p * 64 + k0 + 0];
        float4 hb = *(const float4*)&hbuf[p * 64 + k0 + 4];
        float4 hc = *(const float4*)&hbuf[p * 64 + k0 + 8];
        float4 hd = *(const float4*)&hbuf[p * 64 + k0 + 12];
        float nxr = 0.f, nxz = 0.f, nxn = 0.f;
        if (s + 1 < 32) {
          const float* xq = &xs[(s + 1) * 192];
          nxr = xq[row]; nxz = xq[64 + row]; nxn = xq[128 + row];
        }
        float dr, dz, dn;
        {
          float4 wa, wbv, wc, wd;
          wa = wv[0][0]; wbv = wv[0][1]; wc = wv[0][2]; wd = wv[0][3];
          dr = (wa.x * ha.x + wa.y * ha.y + wa.z * ha.z + wa.w * ha.w)
             + (wbv.x * hb.x + wbv.y * hb.y + wbv.z * hb.z + wbv.w * hb.w)
             + (wc.x * hc.x + wc.y * hc.y + wc.z * hc.z + wc.w * hc.w)
             + (wd.x * hd.x + wd.y * hd.y + wd.z * hd.z + wd.w * hd.w);
          wa = wv[1][0]; wbv = wv[1][1]; wc = wv[1][2]; wd = wv[1][3];
          dz = (wa.x * ha.x + wa.y * ha.y + wa.z * ha.z + wa.w * ha.w)
             + (wbv.x * hb.x + wbv.y * hb.y + wbv.z * hb.z + wbv.w * hb.w)
             + (wc.x * hc.x + wc.y * hc.y + wc.z * hc.z + wc.w * hc.w)
             + (wd.x * hd.x + wd.y * hd.y + wd.z * hd.z + wd.w * hd.w);
          wa = wv[2][0]; wbv = wv[2][1]; wc = wv[2][2]; wd = wv[2][3];
          dn = (wa.x * ha.x + wa.y * ha.y + wa.z * ha.z + wa.w * ha.w)
             + (wbv.x * hb.x + wbv.y * hb.y + wbv.z * hb.z + wbv.w * hb.w)
             + (wc.x * hc.x + wc.y * hc.y + wc.z * hc.z + wc.w * hc.w)
             + (wd.x * hd.x + wd.y * hd.y + wd.z * hd.z + wd.w * hd.w);
        }
        dr += __shfl_xor(dr, 1); dr += __shfl_xor(dr, 2);
        dz += __shfl_xor(dz, 1); dz += __shfl_xor(dz, 2);
        dn += __shfl_xor(dn, 1); dn += __shfl_xor(dn, 2);
        float rg = sigmoidf_(xr + brr + dr);
        float zg = sigmoidf_(xz + bzz + dz);
        float ng = tanhf_(xn + rg * (bnn + dn));
        h = (1.f - zg) * ng + zg * h;
        if (kc == 0) {
          hbuf[(p ^ 1) * 64 + row] = h;
          obuf[s * 64 + row] = h;
        }
        __syncthreads();
        xr = nxr; xz = nxz; xn = nxn;
      }
    }
#pragma unroll
    for (int i = 0; i < 2; ++i) {
      int f = tid + 256 * i;
      int s = f >> 4;
      int c4 = (f & 15) << 2;
      int tp = Sn - 32 + s;
      int orow = rev ? (Sn - 1 - tp) : tp;
      *(float4*)&out[(size_t)(b * Sn + orow) * 128 + dirOff + c4] = *(const float4*)&obuf[s * 64 + c4];
    }
  } else {
    float* Ks = (float*)smem;           // 128*32
    float* Vs = Ks + 128 * 32;          // 128*32
    const int blk = blockIdx.x - 128;
    const int b = blk >> 3;
    const int qhalf = (blk >> 2) & 1;
    const int split = blk & 3;
    const int k0 = split * 128;
#pragma unroll
    for (int i = 0; i < 4; ++i) {
      int f = tid + 256 * i;
      int row = f >> 3, col = (f & 7) * 4;
      *(float4*)&Ks[row * 32 + col] = *(const float4*)&kb[(size_t)(b * Sn + k0 + row) * 32 + col];
      *(float4*)&Vs[row * 32 + col] = *(const float4*)&vb[(size_t)(b * Sn + k0 + row) * 32 + col];
    }
    const int q = b * Sn + qhalf * 256 + tid;
    float qv[32];
#pragma unroll
    for (int d4 = 0; d4 < 8; ++d4) {
      float4 v = *(const float4*)&qb[(size_t)q * 32 + d4 * 4];
      qv[d4 * 4 + 0] = v.x; qv[d4 * 4 + 1] = v.y; qv[d4 * 4 + 2] = v.z; qv[d4 * 4 + 3] = v.w;
    }
    __syncthreads();
    const float scale = 0.17677669529663687f;
    float m = -1e30f, lsum = 0.f;
    float acc[32] = {};
    for (int kk = 0; kk < 128; ++kk) {
      const float4* kr = (const float4*)&Ks[kk * 32];
      float s = 0.f;
#pragma unroll
      for (int d4 = 0; d4 < 8; ++d4) {
        float4 kv = kr[d4];
        s += qv[d4 * 4 + 0] * kv.x + qv[d4 * 4 + 1] * kv.y + qv[d4 * 4 + 2] * kv.z + qv[d4 * 4 + 3] * kv.w;
      }
      s *= scale;
      float mn = fmaxf(m, s);
      float e1 = __expf(m - mn);
      float p = __expf(s - mn);
      lsum = lsum * e1 + p;
      const float4* vr = (const float4*)&Vs[kk * 32];
#pragma unroll
      for (int d4 = 0; d4 < 8; ++d4) {
        float4 vv = vr[d4];
        acc[d4 * 4 + 0] = acc[d4 * 4 + 0] * e1 + p * vv.x;
        acc[d4 * 4 + 1] = acc[d4 * 4 + 1] * e1 + p * vv.y;
        acc[d4 * 4 + 2] = acc[d4 * 4 + 2] * e1 + p * vv.z;
        acc[d4 * 4 + 3] = acc[d4 * 4 + 3] * e1 + p * vv.w;
      }
      m = mn;
    }
    float* rec = part + ((size_t)q * 4 + split) * 36;
#pragma unroll
    for (int d4 = 0; d4 < 8; ++d4) {
      float4 o = {acc[d4 * 4 + 0], acc[d4 * 4 + 1], acc[d4 * 4 + 2], acc[d4 * 4 + 3]};
      *(float4*)&rec[d4 * 4] = o;
    }
    rec[32] = m;
    rec[33] = lsum;
  }
}

// ---------------- K_C: combine partials + out_proj (R8 form) -----------------
__global__ __launch_bounds__(256) void attn_combine(const float* __restrict__ part,
                                                    const float* __restrict__ Wout,
                                                    const float* __restrict__ bout,
                                                    float* __restrict__ attn) {
  __shared__ float Ws[32 * 32];
  __shared__ float bs[32];
  const int tid = threadIdx.x;
  for (int i = tid; i < 1024; i += 256) Ws[i] = Wout[i];
  if (tid < 32) bs[tid] = bout[tid];
  __syncthreads();
  const int q = blockIdx.x * 256 + tid;
  const float* rec = part + (size_t)q * 4 * 36;
  float m0 = rec[32], m1 = rec[36 + 32], m2 = rec[72 + 32], m3 = rec[108 + 32];
  float M = fmaxf(fmaxf(m0, m1), fmaxf(m2, m3));
  float w0 = __expf(m0 - M), w1 = __expf(m1 - M), w2 = __expf(m2 - M), w3 = __expf(m3 - M);
  float L = rec[33] * w0 + rec[36 + 33] * w1 + rec[72 + 33] * w2 + rec[108 + 33] * w3;
  float inv = 1.f / L;
  float a[32];
#pragma unroll
  for (int d4 = 0; d4 < 8; ++d4) {
    float4 p0 = *(const float4*)&rec[d4 * 4];
    float4 p1 = *(const float4*)&rec[36 + d4 * 4];
    float4 p2 = *(const float4*)&rec[72 + d4 * 4];
    float4 p3 = *(const float4*)&rec[108 + d4 * 4];
    a[d4 * 4 + 0] = (p0.x * w0 + p1.x * w1 + p2.x * w2 + p3.x * w3) * inv;
    a[d4 * 4 + 1] = (p0.y * w0 + p1.y * w1 + p2.y * w2 + p3.y * w3) * inv;
    a[d4 * 4 + 2] = (p0.z * w0 + p1.z * w1 + p2.z * w2 + p3.z * w3) * inv;
    a[d4 * 4 + 3] = (p0.w * w0 + p1.w * w1 + p2.w * w2 + p3.w * w3) * inv;
  }
#pragma unroll
  for (int j = 0; j < 32; ++j) {
    float o = bs[j];
#pragma unroll
    for (int d = 0; d < 32; ++d) o += a[d] * Ws[j * 32 + d];
    attn[(size_t)q * 32 + j] = o;
  }
}

// ---------------- K_D: emissions (R8 form) ------------------------------------
__global__ __launch_bounds__(256) void emis_kernel(const float* __restrict__ lstm,
                                                   const float* __restrict__ attn,
                                                   const float* __restrict__ wcomb,
                                                   const float* __restrict__ Wfuse,
                                                   float* __restrict__ emis) {
  __shared__ float Wc[128 * 16];
  __shared__ float Wf2[32 * 16];
  const int tid = threadIdx.x;
  for (int i = tid; i < 2048; i += 256) Wc[i] = wcomb[i];
  for (int i = tid; i < 512; i += 256) Wf2[i] = Wfuse[16 * 16 + i];
  __syncthreads();
  const int idx = blockIdx.x * 256 + tid;
  float acc[16] = {};
  for (int i = 0; i < 128; i += 4) {
    float4 lv = *(const float4*)&lstm[(size_t)idx * 128 + i];
    float ll[4] = {lv.x, lv.y, lv.z, lv.w};
#pragma unroll
    for (int u = 0; u < 4; ++u)
#pragma unroll
      for (int j = 0; j < 16; ++j) acc[j] += ll[u] * Wc[(i + u) * 16 + j];
  }
  for (int d = 0; d < 32; d += 4) {
    float4 av = *(const float4*)&attn[(size_t)idx * 32 + d];
    float aa[4] = {av.x, av.y, av.z, av.w};
#pragma unroll
    for (int u = 0; u < 4; ++u)
#pragma unroll
      for (int j = 0; j < 16; ++j) acc[j] += aa[u] * Wf2[(d + u) * 16 + j];
  }
#pragma unroll
  for (int j = 0; j < 16; j += 4) {
    float4 o = {acc[j], acc[j + 1], acc[j + 2], acc[j + 3]};
    *(float4*)&emis[(size_t)idx * 16 + j] = o;
  }
}

// ========== K_S: CRF group-product matrices (log-semiring scan) ==============
// blk = b*8+g. Group g covers steps t in [1+64g, min(64+64g,511)].
// P_g[i][j] = (M_{t0} (x) ... (x) M_{t1})[i][j],  M_t[i][j]=tr[i][j]+em_t[j].
// lane (i,j) = (tid>>4, tid&15); P in LDS 16x20 (pad, 16B-aligned rows).
__global__ __launch_bounds__(256) void scan_kernel(const float* __restrict__ emis,
                                                   const float* __restrict__ ctrans,
                                                   float* __restrict__ scanbuf) {
  __shared__ __align__(16) float P[16 * 20];
  const int blk = blockIdx.x;
  const int b = blk >> 3;
  const int g = blk & 7;
  const int tid = threadIdx.x;
  const int i = tid >> 4;
  const int j = tid & 15;
  const int t0 = 1 + 64 * g;
  const int t1 = (64 + 64 * g < 511) ? (64 + 64 * g) : 511;
  float trk[16];
#pragma unroll
  for (int k = 0; k < 16; ++k) trk[k] = ctrans[k * 16 + j];
  P[i * 20 + j] = ctrans[i * 16 + j] + emis[((size_t)(b * Sn + t0)) * Tn + j];
  float em_next = emis[((size_t)(b * Sn + t0 + 1)) * Tn + j];
  __syncthreads();
  float out = 0.f;
  for (int t = t0 + 1; t <= t1; ++t) {
    float4 r0 = *(const float4*)&P[i * 20 + 0];
    float4 r1 = *(const float4*)&P[i * 20 + 4];
    float4 r2 = *(const float4*)&P[i * 20 + 8];
    float4 r3 = *(const float4*)&P[i * 20 + 12];
    float em_t = em_next;
    if (t + 1 <= t1) em_next = emis[((size_t)(b * Sn + t + 1)) * Tn + j];
    float wk[16];
    wk[0] = r0.x + trk[0]; wk[1] = r0.y + trk[1]; wk[2] = r0.z + trk[2]; wk[3] = r0.w + trk[3];
    wk[4] = r1.x + trk[4]; wk[5] = r1.y + trk[5]; wk[6] = r1.z + trk[6]; wk[7] = r1.w + trk[7];
    wk[8] = r2.x + trk[8]; wk[9] = r2.y + trk[9]; wk[10] = r2.z + trk[10]; wk[11] = r2.w + trk[11];
    wk[12] = r3.x + trk[12]; wk[13] = r3.y + trk[13]; wk[14] = r3.z + trk[14]; wk[15] = r3.w + trk[15];
    float m = wk[0];
#pragma unroll
    for (int k = 1; k < 16; ++k) m = fmaxf(m, wk[k]);
    float e = 0.f;
#pragma unroll
    for (int k = 0; k < 16; ++k) e += __expf(wk[k] - m);
    out = m + __logf(e) + em_t;
    __syncthreads();
    P[i * 20 + j] = out;
    __syncthreads();
  }
  scanbuf[((size_t)blk) * 256 + i * 16 + j] = P[i * 20 + j];
}

// ===== K_E: numer (0..63) + denom vector-combine over 8 group mats (64..127) =
__global__ __launch_bounds__(64) void mega_e(const float* __restrict__ emis,
                                             const int* __restrict__ tgt,
                                             const float* __restrict__ cstart,
                                             const float* __restrict__ cend,
                                             const float* __restrict__ ctrans,
                                             const float* __restrict__ scanbuf,
                                             float* __restrict__ numer,
                                             float* __restrict__ denom) {
  if (blockIdx.x < 64) {
    const int b = blockIdx.x, l = threadIdx.x;
    float ssum = 0.f;
    for (int t = l; t < Sn; t += 64) {
      int tg = tgt[b * Sn + t];
      ssum += emis[(size_t)(b * Sn + t) * Tn + tg];
      if (t + 1 < Sn) {
        int tg2 = tgt[b * Sn + t + 1];
        ssum += ctrans[tg * Tn + tg2];
      }
    }
    if (l == 0) ssum += cstart[tgt[b * Sn]] + cend[tgt[b * Sn + Sn - 1]];
    for (int off = 32; off > 0; off >>= 1) ssum += __shfl_down(ssum, off);
    if (l == 0) numer[b] = ssum;
  } else {
    __shared__ __align__(16) float vbuf[16];
    const int b = blockIdx.x - 64;
    const int lane = threadIdx.x;
    const int j = lane & 15;
    float v = cstart[j] + emis[(size_t)(b * Sn) * Tn + j];  // t=0
    if (lane < 16) vbuf[j] = v;
    // single wave: DS ops in program order, no barriers needed
    for (int g = 0; g < 8; ++g) {
      float4 v0 = *(const float4*)&vbuf[0];
      float4 v1 = *(const float4*)&vbuf[4];
      float4 v2 = *(const float4*)&vbuf[8];
      float4 v3 = *(const float4*)&vbuf[12];
      const float* P = scanbuf + ((size_t)(b * 8 + g)) * 256;
      float wk[16];
#pragma unroll
      for (int k = 0; k < 16; ++k) wk[k] = P[k * 16 + j];
      wk[0] += v0.x; wk[1] += v0.y; wk[2] += v0.z; wk[3] += v0.w;
      wk[4] += v1.x; wk[5] += v1.y; wk[6] += v1.z; wk[7] += v1.w;
      wk[8] += v2.x; wk[9] += v2.y; wk[10] += v2.z; wk[11] += v2.w;
      wk[12] += v3.x; wk[13] += v3.y; wk[14] += v3.z; wk[15] += v3.w;
      float m = wk[0];
#pragma unroll
      for (int k = 1; k < 16; ++k) m = fmaxf(m, wk[k]);
      float e = 0.f;
#pragma unroll
      for (int k = 0; k < 16; ++k) e += __expf(wk[k] - m);
      float nv = m + __logf(e);
      if (lane < 16) vbuf[j] = nv;
    }
    float f = vbuf[j] + cend[j];
    float m = f;
    m = fmaxf(m, __shfl_xor(m, 1));
    m = fmaxf(m, __shfl_xor(m, 2));
    m = fmaxf(m, __shfl_xor(m, 4));
    m = fmaxf(m, __shfl_xor(m, 8));
    float e = __expf(f - m);
    e += __shfl_xor(e, 1);
    e += __shfl_xor(e, 2);
    e += __shfl_xor(e, 4);
    e += __shfl_xor(e, 8);
    if (lane == 0) denom[b] = m + __logf(e);
  }
}

// ---------------- K_F: final scalar ------------------------------------------
__global__ __launch_bounds__(64) void final_kernel(const float* __restrict__ numer,
                                                   const float* __restrict__ denom,
                                                   float* __restrict__ out) {
  const int l = threadIdx.x;
  float d = denom[l] - numer[l];
  for (int off = 32; off > 0; off >>= 1) d += __shfl_down(d, off);
  if (l == 0) out[0] = d * (1.f / 64.f);
}

extern "C" void kernel_launch(void* const* d_in, const int* in_sizes, int n_in,
                              void* d_out, int out_size, void* d_ws, size_t ws_size,
                              hipStream_t stream) {
  (void)in_sizes; (void)n_in; (void)out_size; (void)ws_size;
  const float* bert = (const float*)d_in[0];
  const float* in2 = (const float*)d_in[1];
  const int* tgt = (const int*)d_in[2];
  const float* Wih_f = (const float*)d_in[3];
  const float* Whh_f = (const float*)d_in[4];
  const float* bih_f = (const float*)d_in[5];
  const float* bhh_f = (const float*)d_in[6];
  const float* Wih_b = (const float*)d_in[7];
  const float* Whh_b = (const float*)d_in[8];
  const float* bih_b = (const float*)d_in[9];
  const float* bhh_b = (const float*)d_in[10];
  const float* Wdense = (const float*)d_in[11];
  const float* in_proj_w = (const float*)d_in[12];
  const float* in_proj_b = (const float*)d_in[13];
  const float* out_proj_w = (const float*)d_in[14];
  const float* out_proj_b = (const float*)d_in[15];
  const float* Wfuse = (const float*)d_in[16];
  const float* cstart = (const float*)d_in[17];
  const float* cend = (const float*)d_in[18];
  const float* ctrans = (const float*)d_in[19];

  float* ws = (float*)d_ws;
  float* C = ws;                                    // B*S*384
  float* lstm = C + (size_t)Bn * Sn * 384;          // B*S*128
  float* qb = lstm + (size_t)Bn * Sn * 2 * Hn;      // B*S*32
  float* kb = qb + (size_t)Bn * Sn * Pn;
  float* vb = kb + (size_t)Bn * Sn * Pn;
  float* attn = vb + (size_t)Bn * Sn * Pn;          // B*S*32
  float* emis = attn + (size_t)Bn * Sn * Pn;        // B*S*16
  float* wcomb = emis + (size_t)Bn * Sn * Tn;       // 2048
  float* numer = wcomb + 2048;                      // 64
  float* denom = numer + Bn;                        // 64
  float* part = denom + Bn;                         // 32768*4*36 (18.9 MB)
  float* scanbuf = part + (size_t)32768 * 4 * 36;   // 64*8*256 = 131072

  mega_a<<<904, 256, 0, stream>>>(bert, Wih_f, Wih_b, bih_f, bih_b, C,
                                  in2, in_proj_w, in_proj_b, qb, kb, vb,
                                  Wdense, Wfuse, wcomb);
  mega_b<<<640, 256, 0, stream>>>(C, Whh_f, bhh_f, Whh_b, bhh_b, lstm,
                                  qb, kb, vb, part);
  attn_combine<<<Bn * Sn / 256, 256, 0, stream>>>(part, out_proj_w, out_proj_b, attn);
  emis_kernel<<<Bn * Sn / 256, 256, 0, stream>>>(lstm, attn, wcomb, Wfuse, emis);
  scan_kernel<<<Bn * 8, 256, 0, stream>>>(emis, ctrans, scanbuf);
  mega_e<<<128, 64, 0, stream>>>(emis, tgt, cstart, cend, ctrans, scanbuf, numer, denom);
  final_kernel<<<1, 64, 0, stream>>>(numer, denom, (float*)d_out);
}

// Round 14
// 541.761 us; speedup vs baseline: 1.5981x; 1.0066x over previous
//
#include <hip/hip_runtime.h>

#define Bn 64
#define Sn 512
#define EB 768
#define Hn 64
#define G3 192
#define Tn 16
#define Pn 32

__device__ __forceinline__ float sigmoidf_(float x) { return 1.f / (1.f + __expf(-x)); }
__device__ __forceinline__ float tanhf_(float x) { return 1.f - 2.f / (__expf(2.f * x) + 1.f); }

__device__ __forceinline__ unsigned short f2bf(float x) {
  union { float f; unsigned u; } v; v.f = x;
  unsigned r = v.u + 0x7fff + ((v.u >> 16) & 1);  // RNE
  return (unsigned short)(r >> 16);
}

typedef __attribute__((ext_vector_type(8))) short short8;
typedef __attribute__((ext_vector_type(4))) float f32x4;

// ---------------- K0: fp32 -> bf16 convert (bert, Wih_f, Wih_b) --------------
__global__ __launch_bounds__(256) void convert_kernel(const float* __restrict__ bert,
                                                      const float* __restrict__ Wf,
                                                      const float* __restrict__ Wb,
                                                      unsigned short* __restrict__ Abf,
                                                      unsigned short* __restrict__ Wbf) {
  const int blk = blockIdx.x;
  const float* src;
  unsigned short* dst;
  size_t base;
  if (blk < 12288) { src = bert; dst = Abf; base = (size_t)blk * 2048; }
  else if (blk < 12360) { src = Wf; dst = Wbf; base = (size_t)(blk - 12288) * 2048; }
  else { src = Wb; dst = Wbf + 147456; base = (size_t)(blk - 12360) * 2048; }
  size_t e = base + (size_t)threadIdx.x * 8;
  float4 v0 = *(const float4*)&src[e];
  float4 v1 = *(const float4*)&src[e + 4];
  short8 o;
  o[0] = f2bf(v0.x); o[1] = f2bf(v0.y); o[2] = f2bf(v0.z); o[3] = f2bf(v0.w);
  o[4] = f2bf(v1.x); o[5] = f2bf(v1.y); o[6] = f2bf(v1.z); o[7] = f2bf(v1.w);
  *(short8*)&dst[e] = o;
}

// ================= K_A: gemm (0..767) + qkv (768..895) + wcomb (896..903) ====
// gemm: bf16 inputs, +40-pad LDS (<=2-way conflicts), DOUBLE-buffered, ONE
// barrier/iter, next-iter loads issued post-barrier (drain covers ~L2 latency).
__global__ __launch_bounds__(256) void mega_a(const unsigned short* __restrict__ Abf,
                                              const unsigned short* __restrict__ Wbf,
                                              const float* __restrict__ bf,
                                              const float* __restrict__ bb,
                                              float* __restrict__ C,
                                              const float* __restrict__ in2,
                                              const float* __restrict__ Wqkv,
                                              const float* __restrict__ bqkv,
                                              float* __restrict__ qb,
                                              float* __restrict__ kb,
                                              float* __restrict__ vb,
                                              const float* __restrict__ Wdense,
                                              const float* __restrict__ Wfuse,
                                              float* __restrict__ wcomb) {
  __shared__ __align__(16) char smem[40960];
  const int gblk = blockIdx.x;
  const int tid = threadIdx.x;
  if (gblk < 768) {
    unsigned short* As0 = (unsigned short*)smem;   // 128*40
    unsigned short* Bs0 = As0 + 128 * 40;
    unsigned short* As1 = Bs0 + 128 * 40;
    unsigned short* Bs1 = As1 + 128 * 40;
    const int xcd = gblk & 7;
    const int slot = gblk >> 3;
    const int lin = xcd * 96 + slot;
    const int m_tile = lin / 3;
    const int n_tile = lin % 3;
    const int n0 = n_tile * 128;
    const int m0 = m_tile * 128;
    const int wv = tid >> 6;
    const int lane = tid & 63;
    const int wm = (wv >> 1) * 64, wn = (wv & 1) * 64;
    const int fr = lane & 15, fq = lane >> 4;
    const int srow = tid >> 1;
    const int shalf = (tid & 1) * 16;
    const unsigned short* Arow = Abf + (size_t)(m0 + srow) * EB;
    const unsigned short* Brow = Wbf + (size_t)(n0 + srow) * EB;
    f32x4 acc[4][4];
#pragma unroll
    for (int i = 0; i < 4; ++i)
#pragma unroll
      for (int j = 0; j < 4; ++j) acc[i][j] = (f32x4){0.f, 0.f, 0.f, 0.f};
    short8 ra0 = *(const short8*)&Arow[shalf];
    short8 ra1 = *(const short8*)&Arow[shalf + 8];
    short8 rb0 = *(const short8*)&Brow[shalf];
    short8 rb1 = *(const short8*)&Brow[shalf + 8];
    for (int kt = 0; kt < 24; ++kt) {
      unsigned short* As = (kt & 1) ? As1 : As0;
      unsigned short* Bs = (kt & 1) ? Bs1 : Bs0;
      *(short8*)&As[srow * 40 + shalf] = ra0;
      *(short8*)&As[srow * 40 + shalf + 8] = ra1;
      *(short8*)&Bs[srow * 40 + shalf] = rb0;
      *(short8*)&Bs[srow * 40 + shalf + 8] = rb1;
      __syncthreads();
      if (kt + 1 < 24) {
        const int k0 = (kt + 1) * 32;
        ra0 = *(const short8*)&Arow[k0 + shalf];
        ra1 = *(const short8*)&Arow[k0 + shalf + 8];
        rb0 = *(const short8*)&Brow[k0 + shalf];
        rb1 = *(const short8*)&Brow[k0 + shalf + 8];
      }
      short8 af[4], bfv[4];
#pragma unroll
      for (int i = 0; i < 4; ++i) af[i] = *(short8*)&As[(wm + i * 16 + fr) * 40 + fq * 8];
#pragma unroll
      for (int j = 0; j < 4; ++j) bfv[j] = *(short8*)&Bs[(wn + j * 16 + fr) * 40 + fq * 8];
#pragma unroll
      for (int i = 0; i < 4; ++i)
#pragma unroll
        for (int j = 0; j < 4; ++j)
          acc[i][j] = __builtin_amdgcn_mfma_f32_16x16x32_bf16(af[i], bfv[j], acc[i][j], 0, 0, 0);
    }
#pragma unroll
    for (int j = 0; j < 4; ++j) {
      int col = n0 + wn + j * 16 + fr;
      float bias = (col < G3) ? bf[col] : bb[col - G3];
#pragma unroll
      for (int i = 0; i < 4; ++i) {
        int rowb = m0 + wm + i * 16 + fq * 4;
#pragma unroll
        for (int rg = 0; rg < 4; ++rg)
          C[(size_t)(rowb + rg) * 384 + col] = acc[i][j][rg] + bias;
      }
    }
  } else if (gblk < 896) {
    float* Ws = (float*)smem;          // 96*32
    float* bs = Ws + 96 * 32;          // 96
    for (int i = tid; i < 96 * 32; i += 256) Ws[i] = Wqkv[i];
    if (tid < 96) bs[tid] = bqkv[tid];
    __syncthreads();
    const int idx = (gblk - 768) * 256 + tid;
    float x[32];
#pragma unroll
    for (int d4 = 0; d4 < 8; ++d4) {
      float4 v = *(const float4*)&in2[(size_t)idx * 32 + d4 * 4];
      x[d4 * 4 + 0] = v.x; x[d4 * 4 + 1] = v.y; x[d4 * 4 + 2] = v.z; x[d4 * 4 + 3] = v.w;
    }
    float* const dsts[3] = {qb, kb, vb};
#pragma unroll
    for (int p = 0; p < 3; ++p) {
      float a[32];
#pragma unroll
      for (int j = 0; j < 32; ++j) {
        float s = bs[p * 32 + j];
#pragma unroll
        for (int d = 0; d < 32; ++d) s += x[d] * Ws[(p * 32 + j) * 32 + d];
        a[j] = s;
      }
      float* dst = dsts[p];
#pragma unroll
      for (int j4 = 0; j4 < 8; ++j4) {
        float4 o = {a[j4 * 4 + 0], a[j4 * 4 + 1], a[j4 * 4 + 2], a[j4 * 4 + 3]};
        *(float4*)&dst[(size_t)idx * 32 + j4 * 4] = o;
      }
    }
  } else {
    int e = (gblk - 896) * 256 + tid;
    int i = e >> 4, j = e & 15;
    float a = 0.f;
#pragma unroll
    for (int c = 0; c < 16; ++c) a += Wdense[i * 16 + c] * Wfuse[c * 16 + j];
    wcomb[e] = a;
  }
}

// ================= K_B: gru (0..127) + attn_split (128..639) =================
__global__ __launch_bounds__(256, 1) void mega_b(const float* __restrict__ C,
                                                 const float* __restrict__ Whh_f,
                                                 const float* __restrict__ bhh_f,
                                                 const float* __restrict__ Whh_b,
                                                 const float* __restrict__ bhh_b,
                                                 float* __restrict__ out,
                                                 const float* __restrict__ qb,
                                                 const float* __restrict__ kb,
                                                 const float* __restrict__ vb,
                                                 float* __restrict__ part) {
  __shared__ __align__(16) char smem[33280];
  const int tid = threadIdx.x;
  if (blockIdx.x < 128) {
    float* xs = (float*)smem;            // 32*192
    float* hbuf = xs + 32 * 192;         // 2*64
    float* obuf = hbuf + 128;            // 32*64
    const int wg = blockIdx.x;
    const int rev = (wg >= Bn) ? 1 : 0;
    const int b = wg & (Bn - 1);
    const int w = tid >> 6;
    const int lane = tid & 63;
    const int r = lane >> 2;
    const int kc = lane & 3;
    const int row = 16 * w + r;
    const int k0 = 16 * kc;
    const float* Whh = rev ? Whh_b : Whh_f;
    const float* bhh = rev ? bhh_b : bhh_f;
    const int colBase = rev ? G3 : 0;
    const int dirOff = rev ? Hn : 0;
    float4 wv[3][4];
#pragma unroll
    for (int g = 0; g < 3; ++g)
#pragma unroll
      for (int q = 0; q < 4; ++q) {
        wv[g][q] = *(const float4*)&Whh[(size_t)(g * 64 + row) * 64 + k0 + 4 * q];
        asm volatile("" : "+v"(wv[g][q].x), "+v"(wv[g][q].y), "+v"(wv[g][q].z), "+v"(wv[g][q].w));
      }
    const float brr = bhh[row], bzz = bhh[64 + row], bnn = bhh[128 + row];
    if (tid < 64) { hbuf[tid] = 0.f; hbuf[64 + tid] = 0.f; }
    float h = 0.f;
    for (int c = 0; c < 16; ++c) {
      const int cstart = c * 32;
      if (c > 0) {
#pragma unroll
        for (int i = 0; i < 2; ++i) {
          int f = tid + 256 * i;
          int s = f >> 4;
          int c4 = (f & 15) << 2;
          int tp = cstart - 32 + s;
          int orow = rev ? (Sn - 1 - tp) : tp;
          *(float4*)&out[(size_t)(b * Sn + orow) * 128 + dirOff + c4] = *(const float4*)&obuf[s * 64 + c4];
        }
      }
      float4 st[6];
#pragma unroll
      for (int i = 0; i < 6; ++i) {
        int f = tid + 256 * i;
        int s = f / 48;
        int c4 = (f % 48) << 2;
        int t = cstart + s;
        int grow = rev ? (Sn - 1 - t) : t;
        st[i] = *(const float4*)&C[(size_t)(b * Sn + grow) * 384 + colBase + c4];
      }
#pragma unroll
      for (int i = 0; i < 6; ++i) {
        int f = tid + 256 * i;
        int s = f / 48;
        int c4 = (f % 48) << 2;
        *(float4*)&xs[s * 192 + c4] = st[i];
      }
      __syncthreads();
      float xr = xs[row], xz = xs[64 + row], xn = xs[128 + row];
      for (int s = 0; s < 32; ++s) {
        const int t = cstart + s;
        const int p = t & 1;
        float4 ha = *(const float4*)&hbuf[p * 64 + k0 + 0];
        float4 hb = *(const float4*)&hbuf[p * 64 + k0 + 4];
        float4 hc = *(const float4*)&hbuf[p * 64 + k0 + 8];
        float4 hd = *(const float4*)&hbuf[p * 64 + k0 + 12];
        float nxr = 0.f, nxz = 0.f, nxn = 0.f;
        if (s + 1 < 32) {
          const float* xq = &xs[(s + 1) * 192];
          nxr = xq[row]; nxz = xq[64 + row]; nxn = xq[128 + row];
        }
        float dr, dz, dn;
        {
          float4 wa, wbv, wc, wd;
          wa = wv[0][0]; wbv = wv[0][1]; wc = wv[0][2]; wd = wv[0][3];
          dr = (wa.x * ha.x + wa.y * ha.y + wa.z * ha.z + wa.w * ha.w)
             + (wbv.x * hb.x + wbv.y * hb.y + wbv.z * hb.z + wbv.w * hb.w)
             + (wc.x * hc.x + wc.y * hc.y + wc.z * hc.z + wc.w * hc.w)
             + (wd.x * hd.x + wd.y * hd.y + wd.z * hd.z + wd.w * hd.w);
          wa = wv[1][0]; wbv = wv[1][1]; wc = wv[1][2]; wd = wv[1][3];
          dz = (wa.x * ha.x + wa.y * ha.y + wa.z * ha.z + wa.w * ha.w)
             + (wbv.x * hb.x + wbv.y * hb.y + wbv.z * hb.z + wbv.w * hb.w)
             + (wc.x * hc.x + wc.y * hc.y + wc.z * hc.z + wc.w * hc.w)
             + (wd.x * hd.x + wd.y * hd.y + wd.z * hd.z + wd.w * hd.w);
          wa = wv[2][0]; wbv = wv[2][1]; wc = wv[2][2]; wd = wv[2][3];
          dn = (wa.x * ha.x + wa.y * ha.y + wa.z * ha.z + wa.w * ha.w)
             + (wbv.x * hb.x + wbv.y * hb.y + wbv.z * hb.z + wbv.w * hb.w)
             + (wc.x * hc.x + wc.y * hc.y + wc.z * hc.z + wc.w * hc.w)
             + (wd.x * hd.x + wd.y * hd.y + wd.z * hd.z + wd.w * hd.w);
        }
        dr += __shfl_xor(dr, 1); dr += __shfl_xor(dr, 2);
        dz += __shfl_xor(dz, 1); dz += __shfl_xor(dz, 2);
        dn += __shfl_xor(dn, 1); dn += __shfl_xor(dn, 2);
        float rg = sigmoidf_(xr + brr + dr);
        float zg = sigmoidf_(xz + bzz + dz);
        float ng = tanhf_(xn + rg * (bnn + dn));
        h = (1.f - zg) * ng + zg * h;
        if (kc == 0) {
          hbuf[(p ^ 1) * 64 + row] = h;
          obuf[s * 64 + row] = h;
        }
        __syncthreads();
        xr = nxr; xz = nxz; xn = nxn;
      }
    }
#pragma unroll
    for (int i = 0; i < 2; ++i) {
      int f = tid + 256 * i;
      int s = f >> 4;
      int c4 = (f & 15) << 2;
      int tp = Sn - 32 + s;
      int orow = rev ? (Sn - 1 - tp) : tp;
      *(float4*)&out[(size_t)(b * Sn + orow) * 128 + dirOff + c4] = *(const float4*)&obuf[s * 64 + c4];
    }
  } else {
    float* Ks = (float*)smem;           // 128*32
    float* Vs = Ks + 128 * 32;          // 128*32
    const int blk = blockIdx.x - 128;
    const int b = blk >> 3;
    const int qhalf = (blk >> 2) & 1;
    const int split = blk & 3;
    const int k0 = split * 128;
#pragma unroll
    for (int i = 0; i < 4; ++i) {
      int f = tid + 256 * i;
      int row = f >> 3, col = (f & 7) * 4;
      *(float4*)&Ks[row * 32 + col] = *(const float4*)&kb[(size_t)(b * Sn + k0 + row) * 32 + col];
      *(float4*)&Vs[row * 32 + col] = *(const float4*)&vb[(size_t)(b * Sn + k0 + row) * 32 + col];
    }
    const int q = b * Sn + qhalf * 256 + tid;
    float qv[32];
#pragma unroll
    for (int d4 = 0; d4 < 8; ++d4) {
      float4 v = *(const float4*)&qb[(size_t)q * 32 + d4 * 4];
      qv[d4 * 4 + 0] = v.x; qv[d4 * 4 + 1] = v.y; qv[d4 * 4 + 2] = v.z; qv[d4 * 4 + 3] = v.w;
    }
    __syncthreads();
    const float scale = 0.17677669529663687f;
    float m = -1e30f, lsum = 0.f;
    float acc[32] = {};
    for (int kk = 0; kk < 128; ++kk) {
      const float4* kr = (const float4*)&Ks[kk * 32];
      float s = 0.f;
#pragma unroll
      for (int d4 = 0; d4 < 8; ++d4) {
        float4 kv = kr[d4];
        s += qv[d4 * 4 + 0] * kv.x + qv[d4 * 4 + 1] * kv.y + qv[d4 * 4 + 2] * kv.z + qv[d4 * 4 + 3] * kv.w;
      }
      s *= scale;
      float mn = fmaxf(m, s);
      float e1 = __expf(m - mn);
      float p = __expf(s - mn);
      lsum = lsum * e1 + p;
      const float4* vr = (const float4*)&Vs[kk * 32];
#pragma unroll
      for (int d4 = 0; d4 < 8; ++d4) {
        float4 vv = vr[d4];
        acc[d4 * 4 + 0] = acc[d4 * 4 + 0] * e1 + p * vv.x;
        acc[d4 * 4 + 1] = acc[d4 * 4 + 1] * e1 + p * vv.y;
        acc[d4 * 4 + 2] = acc[d4 * 4 + 2] * e1 + p * vv.z;
        acc[d4 * 4 + 3] = acc[d4 * 4 + 3] * e1 + p * vv.w;
      }
      m = mn;
    }
    float* rec = part + ((size_t)q * 4 + split) * 36;
#pragma unroll
    for (int d4 = 0; d4 < 8; ++d4) {
      float4 o = {acc[d4 * 4 + 0], acc[d4 * 4 + 1], acc[d4 * 4 + 2], acc[d4 * 4 + 3]};
      *(float4*)&rec[d4 * 4] = o;
    }
    rec[32] = m;
    rec[33] = lsum;
  }
}

// ---------------- K_C: combine partials + out_proj ---------------------------
__global__ __launch_bounds__(256) void attn_combine(const float* __restrict__ part,
                                                    const float* __restrict__ Wout,
                                                    const float* __restrict__ bout,
                                                    float* __restrict__ attn) {
  __shared__ float Ws[32 * 32];
  __shared__ float bs[32];
  const int tid = threadIdx.x;
  for (int i = tid; i < 1024; i += 256) Ws[i] = Wout[i];
  if (tid < 32) bs[tid] = bout[tid];
  __syncthreads();
  const int q = blockIdx.x * 256 + tid;
  const float* rec = part + (size_t)q * 4 * 36;
  float m0 = rec[32], m1 = rec[36 + 32], m2 = rec[72 + 32], m3 = rec[108 + 32];
  float M = fmaxf(fmaxf(m0, m1), fmaxf(m2, m3));
  float w0 = __expf(m0 - M), w1 = __expf(m1 - M), w2 = __expf(m2 - M), w3 = __expf(m3 - M);
  float L = rec[33] * w0 + rec[36 + 33] * w1 + rec[72 + 33] * w2 + rec[108 + 33] * w3;
  float inv = 1.f / L;
  float a[32];
#pragma unroll
  for (int d4 = 0; d4 < 8; ++d4) {
    float4 p0 = *(const float4*)&rec[d4 * 4];
    float4 p1 = *(const float4*)&rec[36 + d4 * 4];
    float4 p2 = *(const float4*)&rec[72 + d4 * 4];
    float4 p3 = *(const float4*)&rec[108 + d4 * 4];
    a[d4 * 4 + 0] = (p0.x * w0 + p1.x * w1 + p2.x * w2 + p3.x * w3) * inv;
    a[d4 * 4 + 1] = (p0.y * w0 + p1.y * w1 + p2.y * w2 + p3.y * w3) * inv;
    a[d4 * 4 + 2] = (p0.z * w0 + p1.z * w1 + p2.z * w2 + p3.z * w3) * inv;
    a[d4 * 4 + 3] = (p0.w * w0 + p1.w * w1 + p2.w * w2 + p3.w * w3) * inv;
  }
#pragma unroll
  for (int j = 0; j < 32; ++j) {
    float o = bs[j];
#pragma unroll
    for (int d = 0; d < 32; ++d) o += a[d] * Ws[j * 32 + d];
    attn[(size_t)q * 32 + j] = o;
  }
}

// ---------------- K_D: emissions ---------------------------------------------
__global__ __launch_bounds__(256) void emis_kernel(const float* __restrict__ lstm,
                                                   const float* __restrict__ attn,
                                                   const float* __restrict__ wcomb,
                                                   const float* __restrict__ Wfuse,
                                                   float* __restrict__ emis) {
  __shared__ float Wc[128 * 16];
  __shared__ float Wf2[32 * 16];
  const int tid = threadIdx.x;
  for (int i = tid; i < 2048; i += 256) Wc[i] = wcomb[i];
  for (int i = tid; i < 512; i += 256) Wf2[i] = Wfuse[16 * 16 + i];
  __syncthreads();
  const int idx = blockIdx.x * 256 + tid;
  float acc[16] = {};
  for (int i = 0; i < 128; i += 4) {
    float4 lv = *(const float4*)&lstm[(size_t)idx * 128 + i];
    float ll[4] = {lv.x, lv.y, lv.z, lv.w};
#pragma unroll
    for (int u = 0; u < 4; ++u)
#pragma unroll
      for (int j = 0; j < 16; ++j) acc[j] += ll[u] * Wc[(i + u) * 16 + j];
  }
  for (int d = 0; d < 32; d += 4) {
    float4 av = *(const float4*)&attn[(size_t)idx * 32 + d];
    float aa[4] = {av.x, av.y, av.z, av.w};
#pragma unroll
    for (int u = 0; u < 4; ++u)
#pragma unroll
      for (int j = 0; j < 16; ++j) acc[j] += aa[u] * Wf2[(d + u) * 16 + j];
  }
#pragma unroll
  for (int j = 0; j < 16; j += 4) {
    float4 o = {acc[j], acc[j + 1], acc[j + 2], acc[j + 3]};
    *(float4*)&emis[(size_t)idx * 16 + j] = o;
  }
}

// ========== K_S: CRF group-product matrices (log-semiring scan) ==============
__global__ __launch_bounds__(256) void scan_kernel(const float* __restrict__ emis,
                                                   const float* __restrict__ ctrans,
                                                   float* __restrict__ scanbuf) {
  __shared__ __align__(16) float P[16 * 20];
  const int blk = blockIdx.x;
  const int b = blk >> 3;
  const int g = blk & 7;
  const int tid = threadIdx.x;
  const int i = tid >> 4;
  const int j = tid & 15;
  const int t0 = 1 + 64 * g;
  const int t1 = (64 + 64 * g < 511) ? (64 + 64 * g) : 511;
  float trk[16];
#pragma unroll
  for (int k = 0; k < 16; ++k) trk[k] = ctrans[k * 16 + j];
  P[i * 20 + j] = ctrans[i * 16 + j] + emis[((size_t)(b * Sn + t0)) * Tn + j];
  float em_next = emis[((size_t)(b * Sn + t0 + 1)) * Tn + j];
  __syncthreads();
  float out = 0.f;
  for (int t = t0 + 1; t <= t1; ++t) {
    float4 r0 = *(const float4*)&P[i * 20 + 0];
    float4 r1 = *(const float4*)&P[i * 20 + 4];
    float4 r2 = *(const float4*)&P[i * 20 + 8];
    float4 r3 = *(const float4*)&P[i * 20 + 12];
    float em_t = em_next;
    if (t + 1 <= t1) em_next = emis[((size_t)(b * Sn + t + 1)) * Tn + j];
    float wk[16];
    wk[0] = r0.x + trk[0]; wk[1] = r0.y + trk[1]; wk[2] = r0.z + trk[2]; wk[3] = r0.w + trk[3];
    wk[4] = r1.x + trk[4]; wk[5] = r1.y + trk[5]; wk[6] = r1.z + trk[6]; wk[7] = r1.w + trk[7];
    wk[8] = r2.x + trk[8]; wk[9] = r2.y + trk[9]; wk[10] = r2.z + trk[10]; wk[11] = r2.w + trk[11];
    wk[12] = r3.x + trk[12]; wk[13] = r3.y + trk[13]; wk[14] = r3.z + trk[14]; wk[15] = r3.w + trk[15];
    float m = wk[0];
#pragma unroll
    for (int k = 1; k < 16; ++k) m = fmaxf(m, wk[k]);
    float e = 0.f;
#pragma unroll
    for (int k = 0; k < 16; ++k) e += __expf(wk[k] - m);
    out = m + __logf(e) + em_t;
    __syncthreads();
    P[i * 20 + j] = out;
    __syncthreads();
  }
  scanbuf[((size_t)blk) * 256 + i * 16 + j] = P[i * 20 + j];
}

// ===== K_E: numer (0..63) + denom vector-combine over 8 group mats (64..127) =
__global__ __launch_bounds__(64) void mega_e(const float* __restrict__ emis,
                                             const int* __restrict__ tgt,
                                             const float* __restrict__ cstart,
                                             const float* __restrict__ cend,
                                             const float* __restrict__ ctrans,
                                             const float* __restrict__ scanbuf,
                                             float* __restrict__ numer,
                                             float* __restrict__ denom) {
  if (blockIdx.x < 64) {
    const int b = blockIdx.x, l = threadIdx.x;
    float ssum = 0.f;
    for (int t = l; t < Sn; t += 64) {
      int tg = tgt[b * Sn + t];
      ssum += emis[(size_t)(b * Sn + t) * Tn + tg];
      if (t + 1 < Sn) {
        int tg2 = tgt[b * Sn + t + 1];
        ssum += ctrans[tg * Tn + tg2];
      }
    }
    if (l == 0) ssum += cstart[tgt[b * Sn]] + cend[tgt[b * Sn + Sn - 1]];
    for (int off = 32; off > 0; off >>= 1) ssum += __shfl_down(ssum, off);
    if (l == 0) numer[b] = ssum;
  } else {
    __shared__ __align__(16) float vbuf[16];
    const int b = blockIdx.x - 64;
    const int lane = threadIdx.x;
    const int j = lane & 15;
    float v = cstart[j] + emis[(size_t)(b * Sn) * Tn + j];  // t=0
    if (lane < 16) vbuf[j] = v;
    for (int g = 0; g < 8; ++g) {
      float4 v0 = *(const float4*)&vbuf[0];
      float4 v1 = *(const float4*)&vbuf[4];
      float4 v2 = *(const float4*)&vbuf[8];
      float4 v3 = *(const float4*)&vbuf[12];
      const float* P = scanbuf + ((size_t)(b * 8 + g)) * 256;
      float wk[16];
#pragma unroll
      for (int k = 0; k < 16; ++k) wk[k] = P[k * 16 + j];
      wk[0] += v0.x; wk[1] += v0.y; wk[2] += v0.z; wk[3] += v0.w;
      wk[4] += v1.x; wk[5] += v1.y; wk[6] += v1.z; wk[7] += v1.w;
      wk[8] += v2.x; wk[9] += v2.y; wk[10] += v2.z; wk[11] += v2.w;
      wk[12] += v3.x; wk[13] += v3.y; wk[14] += v3.z; wk[15] += v3.w;
      float m = wk[0];
#pragma unroll
      for (int k = 1; k < 16; ++k) m = fmaxf(m, wk[k]);
      float e = 0.f;
#pragma unroll
      for (int k = 0; k < 16; ++k) e += __expf(wk[k] - m);
      float nv = m + __logf(e);
      if (lane < 16) vbuf[j] = nv;
    }
    float f = vbuf[j] + cend[j];
    float m = f;
    m = fmaxf(m, __shfl_xor(m, 1));
    m = fmaxf(m, __shfl_xor(m, 2));
    m = fmaxf(m, __shfl_xor(m, 4));
    m = fmaxf(m, __shfl_xor(m, 8));
    float e = __expf(f - m);
    e += __shfl_xor(e, 1);
    e += __shfl_xor(e, 2);
    e += __shfl_xor(e, 4);
    e += __shfl_xor(e, 8);
    if (lane == 0) denom[b] = m + __logf(e);
  }
}

// ---------------- K_F: final scalar ------------------------------------------
__global__ __launch_bounds__(64) void final_kernel(const float* __restrict__ numer,
                                                   const float* __restrict__ denom,
                                                   float* __restrict__ out) {
  const int l = threadIdx.x;
  float d = denom[l] - numer[l];
  for (int off = 32; off > 0; off >>= 1) d += __shfl_down(d, off);
  if (l == 0) out[0] = d * (1.f / 64.f);
}

extern "C" void kernel_launch(void* const* d_in, const int* in_sizes, int n_in,
                              void* d_out, int out_size, void* d_ws, size_t ws_size,
                              hipStream_t stream) {
  (void)in_sizes; (void)n_in; (void)out_size; (void)ws_size;
  const float* bert = (const float*)d_in[0];
  const float* in2 = (const float*)d_in[1];
  const int* tgt = (const int*)d_in[2];
  const float* Wih_f = (const float*)d_in[3];
  const float* Whh_f = (const float*)d_in[4];
  const float* bih_f = (const float*)d_in[5];
  const float* bhh_f = (const float*)d_in[6];
  const float* Wih_b = (const float*)d_in[7];
  const float* Whh_b = (const float*)d_in[8];
  const float* bih_b = (const float*)d_in[9];
  const float* bhh_b = (const float*)d_in[10];
  const float* Wdense = (const float*)d_in[11];
  const float* in_proj_w = (const float*)d_in[12];
  const float* in_proj_b = (const float*)d_in[13];
  const float* out_proj_w = (const float*)d_in[14];
  const float* out_proj_b = (const float*)d_in[15];
  const float* Wfuse = (const float*)d_in[16];
  const float* cstart = (const float*)d_in[17];
  const float* cend = (const float*)d_in[18];
  const float* ctrans = (const float*)d_in[19];

  float* ws = (float*)d_ws;
  float* C = ws;                                    // 12,582,912
  float* lstm = C + (size_t)12582912;               //  4,194,304
  float* qb = lstm + (size_t)4194304;               //  1,048,576
  float* kb = qb + (size_t)1048576;
  float* vb = kb + (size_t)1048576;
  float* emis = vb + (size_t)1048576;               //    524,288
  float* wcomb = emis + (size_t)524288;             //      2,048
  float* numer = wcomb + 2048;                      //         64
  float* denom = numer + 64;                        //         64
  // region: Abf (25,165,824 bf16 = 12,582,912 floats). Dead after mega_a;
  // part/scanbuf/attn alias it (all written after mega_a completes).
  float* region = denom + 64;
  unsigned short* Abf = (unsigned short*)region;
  float* part = region;                             // 4,718,592
  float* scanbuf = part + (size_t)4718592;          //   131,072
  float* attn = scanbuf + (size_t)131072;           // 1,048,576  (< 12.58M total)
  unsigned short* Wbf = (unsigned short*)(region + (size_t)12582912);  // 294,912 bf16

  convert_kernel<<<12432, 256, 0, stream>>>(bert, Wih_f, Wih_b, Abf, Wbf);
  mega_a<<<904, 256, 0, stream>>>(Abf, Wbf, bih_f, bih_b, C,
                                  in2, in_proj_w, in_proj_b, qb, kb, vb,
                                  Wdense, Wfuse, wcomb);
  mega_b<<<640, 256, 0, stream>>>(C, Whh_f, bhh_f, Whh_b, bhh_b, lstm,
                                  qb, kb, vb, part);
  attn_combine<<<Bn * Sn / 256, 256, 0, stream>>>(part, out_proj_w, out_proj_b, attn);
  emis_kernel<<<Bn * Sn / 256, 256, 0, stream>>>(lstm, attn, wcomb, Wfuse, emis);
  scan_kernel<<<Bn * 8, 256, 0, stream>>>(emis, ctrans, scanbuf);
  mega_e<<<128, 64, 0, stream>>>(emis, tgt, cstart, cend, ctrans, scanbuf, numer, denom);
  final_kernel<<<1, 64, 0, stream>>>(numer, denom, (float*)d_out);
}